// Round 1
// baseline (1076.750 us; speedup 1.0000x reference)
//
#include <hip/hip_runtime.h>

#define NN 4096
#define EE 131072
#define NP1 2048
#define NP2 1024

// ---------------- small utility kernels ----------------

__global__ void hist_kernel(const int* __restrict__ src, const int* __restrict__ dst,
                            int* __restrict__ cnt_src, int* __restrict__ cnt_dst, int E) {
  int e = blockIdx.x * blockDim.x + threadIdx.x;
  if (e < E) {
    atomicAdd(&cnt_src[src[e]], 1);
    atomicAdd(&cnt_dst[dst[e]], 1);
  }
}

__global__ __launch_bounds__(1024) void scan_kernel(const int* __restrict__ in, int* __restrict__ out, int n) {
  // exclusive scan, n <= 4096, single block of 1024 threads
  __shared__ int tmp[4096];
  int tid = threadIdx.x;
  for (int i = tid; i < n; i += 1024) tmp[i] = in[i];
  __syncthreads();
  for (int off = 1; off < n; off <<= 1) {
    int v[4];
    int c = 0;
    for (int i = tid; i < n; i += 1024) { v[c++] = (i >= off) ? tmp[i - off] : 0; }
    __syncthreads();
    c = 0;
    for (int i = tid; i < n; i += 1024) { tmp[i] += v[c++]; }
    __syncthreads();
  }
  for (int i = tid; i < n; i += 1024) out[i + 1] = tmp[i];
  if (tid == 0) out[0] = 0;
}

__global__ void scatter_kernel(const int* __restrict__ src, const int* __restrict__ dst,
                               const int* __restrict__ csc_off, const int* __restrict__ csr_off,
                               int* __restrict__ fill_dst, int* __restrict__ fill_src,
                               int* __restrict__ csc_src, int* __restrict__ csr_dst, int E) {
  int e = blockIdx.x * blockDim.x + threadIdx.x;
  if (e < E) {
    int s = src[e], d = dst[e];
    int p = atomicAdd(&fill_dst[d], 1);
    csc_src[csc_off[d] + p] = s;
    int q = atomicAdd(&fill_src[s], 1);
    csr_dst[csr_off[s] + q] = d;
  }
}

__global__ void dis0_kernel(const int* __restrict__ cnt_dst, float* __restrict__ dis, int n) {
  int i = blockIdx.x * blockDim.x + threadIdx.x;
  if (i < n) dis[i] = rsqrtf((float)cnt_dst[i] + 1.0f);
}

__global__ void pnorm_kernel(const float* __restrict__ p, float* __restrict__ outv, int C) {
  int tid = threadIdx.x;  // 256 threads
  float acc = 0.f;
  for (int j = tid; j < C; j += 256) { float v = p[j]; acc += v * v; }
  for (int o = 32; o > 0; o >>= 1) acc += __shfl_down(acc, o);
  __shared__ float red[4];
  if ((tid & 63) == 0) red[tid >> 6] = acc;
  __syncthreads();
  if (tid == 0) outv[0] = sqrtf(red[0] + red[1] + red[2] + red[3]);
}

__global__ void score_kernel(const float* __restrict__ X, const float* __restrict__ p,
                             const float* __restrict__ pn, float* __restrict__ s, int C) {
  int i = blockIdx.x;
  int tid = threadIdx.x;  // 256
  float acc = 0.f;
  for (int j = tid; j < C; j += 256) acc += X[(size_t)i * C + j] * p[j];
  for (int o = 32; o > 0; o >>= 1) acc += __shfl_down(acc, o);
  __shared__ float red[4];
  if ((tid & 63) == 0) red[tid >> 6] = acc;
  __syncthreads();
  if (tid == 0) s[i] = tanhf((red[0] + red[1] + red[2] + red[3]) / pn[0]);
}

__global__ __launch_bounds__(1024) void rank_kernel(const float* __restrict__ s, int n, int k,
                            int* __restrict__ kept, int* __restrict__ perm, float* __restrict__ vals) {
  extern __shared__ unsigned long long keys[];
  int i = blockIdx.x * blockDim.x + threadIdx.x;
  for (int t = threadIdx.x; t < n; t += blockDim.x) {
    unsigned u = __float_as_uint(s[t]);
    unsigned m = (u & 0x80000000u) ? ~u : (u | 0x80000000u);
    keys[t] = (((unsigned long long)(~m)) << 32) | (unsigned)t;  // desc value, asc index
  }
  __syncthreads();
  if (i < n) {
    unsigned long long ki = keys[i];
    int r = 0;
    for (int t = 0; t < n; ++t) r += (keys[t] < ki) ? 1 : 0;
    if (r < k) { perm[r] = i; vals[r] = s[i]; kept[i] = r; }
    else kept[i] = -1;
  }
}

__global__ void pool_gather(const float* __restrict__ X, const int* __restrict__ perm,
                            const float* __restrict__ vals, float* __restrict__ out, int C) {
  int a = blockIdx.x;
  int r = perm[a];
  float v = vals[a];
  for (int j = threadIdx.x; j < C; j += blockDim.x)
    out[(size_t)a * C + j] = X[(size_t)r * C + j] * v;
}

__global__ void aug_pair(const int* __restrict__ csc_off, const int* __restrict__ csc_src,
                         const int* __restrict__ csr_off, const int* __restrict__ csr_dst,
                         const int* __restrict__ kept, float* __restrict__ Bp, int np) {
  int k = blockIdx.x;
  int is = csc_off[k], ni_e = csc_off[k + 1] - is;
  int os = csr_off[k], no_e = csr_off[k + 1] - os;
  int ni = ni_e + 1, no = no_e + 1;  // +1: self loop on each side
  int tot = ni * no;
  for (int p = threadIdx.x; p < tot; p += blockDim.x) {
    int a = p / no, b = p - a * no;
    int i = (a < ni_e) ? csc_src[is + a] : k;
    int j = (b < no_e) ? csr_dst[os + b] : k;
    int ki = kept[i]; if (ki < 0) continue;
    int kj = kept[j]; if (kj < 0) continue;
    atomicAdd(&Bp[(size_t)ki * np + kj], 1.0f);
  }
}

__global__ void adddiag_kernel(float* __restrict__ B, int n) {
  int i = blockIdx.x * blockDim.x + threadIdx.x;
  if (i < n) B[(size_t)i * n + i] += 1.0f;
}

__global__ void colsum_part(const float* __restrict__ B, float* __restrict__ deg, int n, int rows_per) {
  int c = blockIdx.x * blockDim.x + threadIdx.x;
  int r0 = blockIdx.y * rows_per;
  float acc = 0.f;
  for (int r = r0; r < r0 + rows_per; ++r) acc += B[(size_t)r * n + c];
  atomicAdd(&deg[c], acc);
}

__global__ void dis_from_deg(const float* __restrict__ deg, float* __restrict__ dis, int n) {
  int i = blockIdx.x * blockDim.x + threadIdx.x;
  if (i < n) dis[i] = rsqrtf(deg[i]);
}

__global__ void col_gather(const float* __restrict__ B, const int* __restrict__ perm,
                           float* __restrict__ out, int n, int np) {
  int idx = blockIdx.x * blockDim.x + threadIdx.x;  // over n*np
  if (idx < n * np) {
    int t = idx / np, b = idx - t * np;
    out[idx] = B[(size_t)t * n + perm[b]];
  }
}

__global__ void unpool_add(const float* __restrict__ res, const float* __restrict__ up,
                           const int* __restrict__ kept, float* __restrict__ out, int n, int C) {
  int idx = blockIdx.x * blockDim.x + threadIdx.x;
  if (idx < n * C) {
    int r = idx / C;
    int j = idx - r * C;
    int k = kept[r];
    float v = res[idx];
    if (k >= 0) v += up[(size_t)k * C + j];
    out[idx] = v;
  }
}

__global__ void spmm_gather(const float* __restrict__ Y, const int* __restrict__ off,
                            const int* __restrict__ srcs, const float* __restrict__ dis,
                            const float* __restrict__ bias, float* __restrict__ out, int C) {
  int c = blockIdx.x;
  int j = threadIdx.x;  // blockDim == C
  float acc = Y[(size_t)c * C + j];  // self loop (Y pre-scaled by dis)
  int s = off[c], e = off[c + 1];
  for (int t = s; t < e; ++t) acc += Y[(size_t)srcs[t] * C + j];
  out[(size_t)c * C + j] = fmaxf(dis[c] * acc + bias[j], 0.0f);
}

// ---------------- tiled fp32 matmuls (M,N % 64 == 0, K % 16 == 0) ----------------
#define TS 72  // LDS row stride (72*4B = 288B, 16B-aligned for float4)

// C[i][j] = rs[i] * sum_k X[i][k]*W[k][j]
__global__ __launch_bounds__(256) void mm_xw(const float* __restrict__ X, const float* __restrict__ W,
                                             const float* __restrict__ rs, float* __restrict__ C_,
                                             int M, int K, int N) {
  __shared__ float As[16][TS];
  __shared__ float Bs[16][TS];
  int tid = threadIdx.x;
  int ty = tid >> 4, tx = tid & 15;
  int i0 = blockIdx.y * 64, j0 = blockIdx.x * 64;
  int ar = tid >> 4, ak = tid & 15;
  int bk = tid >> 6, bj = tid & 63;
  float acc[4][4] = {};
  for (int k0 = 0; k0 < K; k0 += 16) {
#pragma unroll
    for (int s5 = 0; s5 < 4; ++s5) {
      As[ak][ar + 16 * s5] = X[(size_t)(i0 + ar + 16 * s5) * K + k0 + ak];
      Bs[bk + 4 * s5][bj] = W[(size_t)(k0 + bk + 4 * s5) * N + j0 + bj];
    }
    __syncthreads();
#pragma unroll
    for (int kk = 0; kk < 16; ++kk) {
      float4 a4 = *(const float4*)&As[kk][ty * 4];
      float4 b4 = *(const float4*)&Bs[kk][tx * 4];
      float av[4] = {a4.x, a4.y, a4.z, a4.w};
      float bv[4] = {b4.x, b4.y, b4.z, b4.w};
#pragma unroll
      for (int a = 0; a < 4; ++a)
#pragma unroll
        for (int b = 0; b < 4; ++b) acc[a][b] += av[a] * bv[b];
    }
    __syncthreads();
  }
#pragma unroll
  for (int a = 0; a < 4; ++a) {
    int i = i0 + ty * 4 + a;
    float r = rs[i];
#pragma unroll
    for (int b = 0; b < 4; ++b)
      C_[(size_t)i * N + j0 + tx * 4 + b] = r * acc[a][b];
  }
}

// C[c][j] = relu(ds[c] * sum_r Bm[r][c]*Y[r][j] + bias[j]);  Bm is n x n row-major
__global__ __launch_bounds__(256) void mm_agg(const float* __restrict__ Bm, const float* __restrict__ Y,
                                              const float* __restrict__ ds, const float* __restrict__ bias,
                                              float* __restrict__ C_, int n, int N) {
  __shared__ float As[16][TS];
  __shared__ float Bs[16][TS];
  int tid = threadIdx.x;
  int ty = tid >> 4, tx = tid & 15;
  int i0 = blockIdx.y * 64, j0 = blockIdx.x * 64;
  int bk = tid >> 6, bj = tid & 63;
  float acc[4][4] = {};
  for (int k0 = 0; k0 < n; k0 += 16) {
#pragma unroll
    for (int s5 = 0; s5 < 4; ++s5) {
      As[bk + 4 * s5][bj] = Bm[(size_t)(k0 + bk + 4 * s5) * n + i0 + bj];
      Bs[bk + 4 * s5][bj] = Y[(size_t)(k0 + bk + 4 * s5) * N + j0 + bj];
    }
    __syncthreads();
#pragma unroll
    for (int kk = 0; kk < 16; ++kk) {
      float4 a4 = *(const float4*)&As[kk][ty * 4];
      float4 b4 = *(const float4*)&Bs[kk][tx * 4];
      float av[4] = {a4.x, a4.y, a4.z, a4.w};
      float bv[4] = {b4.x, b4.y, b4.z, b4.w};
#pragma unroll
      for (int a = 0; a < 4; ++a)
#pragma unroll
        for (int b = 0; b < 4; ++b) acc[a][b] += av[a] * bv[b];
    }
    __syncthreads();
  }
#pragma unroll
  for (int a = 0; a < 4; ++a) {
    int i = i0 + ty * 4 + a;
    float d = ds[i];
#pragma unroll
    for (int b = 0; b < 4; ++b) {
      int j = j0 + tx * 4 + b;
      C_[(size_t)i * N + j] = fmaxf(d * acc[a][b] + bias[j], 0.0f);
    }
  }
}

// C[a][b] = sum_t B1[pa[a]][t] * B1c[t][b];  B1 row-stride = K, B1c is K x N
__global__ __launch_bounds__(256) void mm_aug(const float* __restrict__ B1, const float* __restrict__ B1c,
                                              const int* __restrict__ pa, float* __restrict__ C_,
                                              int K, int N) {
  __shared__ float As[16][TS];
  __shared__ float Bs[16][TS];
  int tid = threadIdx.x;
  int ty = tid >> 4, tx = tid & 15;
  int i0 = blockIdx.y * 64, j0 = blockIdx.x * 64;
  int ar = tid >> 4, ak = tid & 15;
  int bk = tid >> 6, bj = tid & 63;
  float acc[4][4] = {};
  for (int k0 = 0; k0 < K; k0 += 16) {
#pragma unroll
    for (int s5 = 0; s5 < 4; ++s5) {
      As[ak][ar + 16 * s5] = B1[(size_t)pa[i0 + ar + 16 * s5] * K + k0 + ak];
      Bs[bk + 4 * s5][bj] = B1c[(size_t)(k0 + bk + 4 * s5) * N + j0 + bj];
    }
    __syncthreads();
#pragma unroll
    for (int kk = 0; kk < 16; ++kk) {
      float4 a4 = *(const float4*)&As[kk][ty * 4];
      float4 b4 = *(const float4*)&Bs[kk][tx * 4];
      float av[4] = {a4.x, a4.y, a4.z, a4.w};
      float bv[4] = {b4.x, b4.y, b4.z, b4.w};
#pragma unroll
      for (int a = 0; a < 4; ++a)
#pragma unroll
        for (int b = 0; b < 4; ++b) acc[a][b] += av[a] * bv[b];
    }
    __syncthreads();
  }
#pragma unroll
  for (int a = 0; a < 4; ++a) {
    int i = i0 + ty * 4 + a;
#pragma unroll
    for (int b = 0; b < 4; ++b)
      C_[(size_t)i * N + j0 + tx * 4 + b] = acc[a][b];
  }
}

// ---------------- launch ----------------

extern "C" void kernel_launch(void* const* d_in, const int* in_sizes, int n_in,
                              void* d_out, int out_size, void* d_ws, size_t ws_size,
                              hipStream_t stream) {
  const float* x  = (const float*)d_in[0];
  const int* ei   = (const int*)d_in[1];
  const int* esrc = ei;
  const int* edst = ei + EE;
  const float* w0 = (const float*)d_in[2];
  const float* b0 = (const float*)d_in[3];
  const float* w1 = (const float*)d_in[4];
  const float* b1 = (const float*)d_in[5];
  const float* w2 = (const float*)d_in[6];
  const float* b2 = (const float*)d_in[7];
  const float* w3 = (const float*)d_in[8];
  const float* b3 = (const float*)d_in[9];
  const float* w4 = (const float*)d_in[10];
  const float* b4 = (const float*)d_in[11];
  const float* p0 = (const float*)d_in[12];
  const float* p1 = (const float*)d_in[13];
  float* out = (float*)d_out;

  char* ws = (char*)d_ws;
  size_t off = 0;
  auto alloc = [&](size_t b) { void* p = ws + off; off += (b + 255) & ~(size_t)255; return p; };

  int* csc_off = (int*)alloc(4 * (NN + 1));
  int* csr_off = (int*)alloc(4 * (NN + 1));
  int* csc_src = (int*)alloc(4 * EE);
  int* csr_dst = (int*)alloc(4 * EE);
  // zeroed region: 4 count arrays + deg1 + deg2
  int* cnts    = (int*)alloc(4 * NN * 4 + 4 * NP1 + 4 * NP2);
  int* cnt_dst = cnts;
  int* cnt_src = cnts + NN;
  int* fill_dst = cnts + 2 * NN;
  int* fill_src = cnts + 3 * NN;
  float* deg1 = (float*)(cnts + 4 * NN);
  float* deg2 = deg1 + NP1;
  size_t zero_bytes = 4 * NN * 4 + 4 * NP1 + 4 * NP2;

  int* kept0 = (int*)alloc(4 * NN);
  int* perm0 = (int*)alloc(4 * NP1);
  int* kept1 = (int*)alloc(4 * NP1);
  int* perm1 = (int*)alloc(4 * NP2);
  float* dis0 = (float*)alloc(4 * NN);
  float* dis1 = (float*)alloc(4 * NP1);
  float* dis2 = (float*)alloc(4 * NP2);
  float* pnrm = (float*)alloc(8);
  float* s0   = (float*)alloc(4 * NN);
  float* vals0 = (float*)alloc(4 * NP1);
  float* s1   = (float*)alloc(4 * NP1);
  float* vals1 = (float*)alloc(4 * NP2);

  float* regA = (float*)alloc((size_t)4 * 1024 * 1024);   // y0 / y1 / {y2,out2} / y4
  float* regB = (float*)alloc((size_t)4 * 1024 * 1024);   // res0
  float* regC = (float*)alloc((size_t)2 * 1024 * 1024);   // x1in / x2in / y3
  float* regD = (float*)alloc((size_t)16 * 1024 * 1024);  // B1
  float* regE = (float*)alloc((size_t)8 * 1024 * 1024);   // B1c / xin3
  float* regF = (float*)alloc((size_t)4 * 1024 * 1024);   // res1 / xin4
  float* regG = (float*)alloc((size_t)4 * 1024 * 1024);   // B2 / out3

  float* y0 = regA;
  float* res0 = regB;
  float* x1in = regC;
  float* B1 = regD;
  float* y1 = regA;
  float* res1 = regF;
  float* x2in = regC;
  float* B1c = regE;
  float* B2 = regG;
  float* y2 = regA;
  float* out2 = regA + (size_t)NP2 * 512;
  float* xin3 = regE;
  float* y3 = regC;
  float* out3 = regG;
  float* xin4 = regF;
  float* y4 = regA;

  hipMemsetAsync(cnts, 0, zero_bytes, stream);
  hipMemsetAsync(B1, 0, (size_t)NP1 * NP1 * 4, stream);

  // CSR/CSC build
  hist_kernel<<<EE / 256, 256, 0, stream>>>(esrc, edst, cnt_src, cnt_dst, EE);
  scan_kernel<<<1, 1024, 0, stream>>>(cnt_dst, csc_off, NN);
  scan_kernel<<<1, 1024, 0, stream>>>(cnt_src, csr_off, NN);
  scatter_kernel<<<EE / 256, 256, 0, stream>>>(esrc, edst, csc_off, csr_off,
                                               fill_dst, fill_src, csc_src, csr_dst, EE);
  dis0_kernel<<<NN / 256, 256, 0, stream>>>(cnt_dst, dis0, NN);
  pnorm_kernel<<<1, 256, 0, stream>>>(p0, pnrm + 0, 256);
  pnorm_kernel<<<1, 256, 0, stream>>>(p1, pnrm + 1, 512);

  // gcn0 (sparse)
  mm_xw<<<dim3(256 / 64, NN / 64), 256, 0, stream>>>(x, w0, dis0, y0, NN, 128, 256);
  spmm_gather<<<NN, 256, 0, stream>>>(y0, csc_off, csc_src, dis0, b0, res0, 256);

  // pool0
  score_kernel<<<NN, 256, 0, stream>>>(res0, p0, pnrm + 0, s0, 256);
  rank_kernel<<<NN / 1024, 1024, NN * 8, stream>>>(s0, NN, NP1, kept0, perm0, vals0);
  pool_gather<<<NP1, 256, 0, stream>>>(res0, perm0, vals0, x1in, 256);

  // augment0 restricted -> B1, then +I, deg, dis
  aug_pair<<<NN, 256, 0, stream>>>(csc_off, csc_src, csr_off, csr_dst, kept0, B1, NP1);
  adddiag_kernel<<<NP1 / 256, 256, 0, stream>>>(B1, NP1);
  colsum_part<<<dim3(NP1 / 256, NP1 / 256), 256, 0, stream>>>(B1, deg1, NP1, 256);
  dis_from_deg<<<NP1 / 256, 256, 0, stream>>>(deg1, dis1, NP1);

  // gcn1 (dense)
  mm_xw<<<dim3(512 / 64, NP1 / 64), 256, 0, stream>>>(x1in, w1, dis1, y1, NP1, 256, 512);
  mm_agg<<<dim3(512 / 64, NP1 / 64), 256, 0, stream>>>(B1, y1, dis1, b1, res1, NP1, 512);

  // pool1
  score_kernel<<<NP1, 256, 0, stream>>>(res1, p1, pnrm + 1, s1, 512);
  rank_kernel<<<NP1 / 1024, 1024, NP1 * 8, stream>>>(s1, NP1, NP2, kept1, perm1, vals1);
  pool_gather<<<NP2, 256, 0, stream>>>(res1, perm1, vals1, x2in, 512);

  // augment1 restricted (dense): B2 = B1[perm1,:] @ B1[:,perm1], then +I, deg, dis
  col_gather<<<(NP1 * NP2) / 256, 256, 0, stream>>>(B1, perm1, B1c, NP1, NP2);
  mm_aug<<<dim3(NP2 / 64, NP2 / 64), 256, 0, stream>>>(B1, B1c, perm1, B2, NP1, NP2);
  adddiag_kernel<<<NP2 / 256, 256, 0, stream>>>(B2, NP2);
  colsum_part<<<dim3(NP2 / 256, NP2 / 256), 256, 0, stream>>>(B2, deg2, NP2, 256);
  dis_from_deg<<<NP2 / 256, 256, 0, stream>>>(deg2, dis2, NP2);

  // gcn2 (bottleneck, dense)
  mm_xw<<<dim3(512 / 64, NP2 / 64), 256, 0, stream>>>(x2in, w2, dis2, y2, NP2, 512, 512);
  mm_agg<<<dim3(512 / 64, NP2 / 64), 256, 0, stream>>>(B2, y2, dis2, b2, out2, NP2, 512);

  // up1: xin3 = res1 + scatter(out2), gcn3 (dense)
  unpool_add<<<(NP1 * 512) / 256, 256, 0, stream>>>(res1, out2, kept1, xin3, NP1, 512);
  mm_xw<<<dim3(256 / 64, NP1 / 64), 256, 0, stream>>>(xin3, w3, dis1, y3, NP1, 512, 256);
  mm_agg<<<dim3(256 / 64, NP1 / 64), 256, 0, stream>>>(B1, y3, dis1, b3, out3, NP1, 256);

  // up0: xin4 = res0 + scatter(out3), gcn4 (sparse) -> d_out
  unpool_add<<<(NN * 256) / 256, 256, 0, stream>>>(res0, out3, kept0, xin4, NN, 256);
  mm_xw<<<dim3(128 / 64, NN / 64), 256, 0, stream>>>(xin4, w4, dis0, y4, NN, 256, 128);
  spmm_gather<<<NN, 128, 0, stream>>>(y4, csc_off, csc_src, dis0, b4, out, 128);
}

// Round 2
// 629.387 us; speedup vs baseline: 1.7108x; 1.7108x over previous
//
#include <hip/hip_runtime.h>

#define NN 4096
#define EE 131072
#define NP1 2048
#define NP2 1024

typedef __attribute__((ext_vector_type(8))) __bf16 bf16x8;
typedef __attribute__((ext_vector_type(4))) float f32x4;

static __device__ inline unsigned short bfbits(__bf16 b) {
  union { __bf16 x; unsigned short u; } c; c.x = b; return c.u;
}
static __device__ inline void split2(float v, unsigned short& h, unsigned short& l) {
  __bf16 hb = (__bf16)v;
  float hf = (float)hb;
  __bf16 lb = (__bf16)(v - hf);
  h = bfbits(hb); l = bfbits(lb);
}

// ---------------- graph build ----------------

__global__ void hist_kernel(const int* __restrict__ src, const int* __restrict__ dst,
                            int* __restrict__ cnt_src, int* __restrict__ cnt_dst, int E) {
  int e = blockIdx.x * blockDim.x + threadIdx.x;
  if (e < E) {
    atomicAdd(&cnt_src[src[e]], 1);
    atomicAdd(&cnt_dst[dst[e]], 1);
  }
}

__global__ __launch_bounds__(1024) void scan_kernel(const int* __restrict__ in, int* __restrict__ out, int n) {
  __shared__ int tmp[4096];
  int tid = threadIdx.x;
  for (int i = tid; i < n; i += 1024) tmp[i] = in[i];
  __syncthreads();
  for (int off = 1; off < n; off <<= 1) {
    int v[4];
    int c = 0;
    for (int i = tid; i < n; i += 1024) { v[c++] = (i >= off) ? tmp[i - off] : 0; }
    __syncthreads();
    c = 0;
    for (int i = tid; i < n; i += 1024) { tmp[i] += v[c++]; }
    __syncthreads();
  }
  for (int i = tid; i < n; i += 1024) out[i + 1] = tmp[i];
  if (tid == 0) out[0] = 0;
}

__global__ void scatter_kernel(const int* __restrict__ src, const int* __restrict__ dst,
                               const int* __restrict__ csc_off, const int* __restrict__ csr_off,
                               int* __restrict__ fill_dst, int* __restrict__ fill_src,
                               int* __restrict__ csc_src, int* __restrict__ csr_dst, int E) {
  int e = blockIdx.x * blockDim.x + threadIdx.x;
  if (e < E) {
    int s = src[e], d = dst[e];
    int p = atomicAdd(&fill_dst[d], 1);
    csc_src[csc_off[d] + p] = s;
    int q = atomicAdd(&fill_src[s], 1);
    csr_dst[csr_off[s] + q] = d;
  }
}

__global__ void dis0_kernel(const int* __restrict__ cnt_dst, float* __restrict__ dis, int n) {
  int i = blockIdx.x * blockDim.x + threadIdx.x;
  if (i < n) dis[i] = rsqrtf((float)cnt_dst[i] + 1.0f);
}

__global__ void pnorm_kernel(const float* __restrict__ p, float* __restrict__ outv, int C) {
  int tid = threadIdx.x;
  float acc = 0.f;
  for (int j = tid; j < C; j += 256) { float v = p[j]; acc += v * v; }
  for (int o = 32; o > 0; o >>= 1) acc += __shfl_down(acc, o);
  __shared__ float red[4];
  if ((tid & 63) == 0) red[tid >> 6] = acc;
  __syncthreads();
  if (tid == 0) outv[0] = sqrtf(red[0] + red[1] + red[2] + red[3]);
}

// ---------------- scoring / topk ----------------

__global__ void score_kernel(const float* __restrict__ X, const float* __restrict__ p,
                             const float* __restrict__ pn, float* __restrict__ s, int C) {
  int i = blockIdx.x;
  int tid = threadIdx.x;
  float acc = 0.f;
  for (int j = tid; j < C; j += 256) acc += X[(size_t)i * C + j] * p[j];
  for (int o = 32; o > 0; o >>= 1) acc += __shfl_down(acc, o);
  __shared__ float red[4];
  if ((tid & 63) == 0) red[tid >> 6] = acc;
  __syncthreads();
  if (tid == 0) s[i] = tanhf((red[0] + red[1] + red[2] + red[3]) / pn[0]);
}

__global__ void key_kernel(const float* __restrict__ s, unsigned long long* __restrict__ keys, int n) {
  int i = blockIdx.x * blockDim.x + threadIdx.x;
  if (i < n) {
    unsigned u = __float_as_uint(s[i]);
    unsigned m = (u & 0x80000000u) ? ~u : (u | 0x80000000u);
    keys[i] = (((unsigned long long)(~m)) << 32) | (unsigned)i;  // desc value, asc index
  }
}

__global__ __launch_bounds__(256) void rank_count(const unsigned long long* __restrict__ keys,
                                                  int* __restrict__ rank) {
  __shared__ unsigned long long kk[512];
  int tid = threadIdx.x;
  int cand = blockIdx.x * 256 + tid;
  int base = blockIdx.y * 512;
  kk[tid] = keys[base + tid];
  kk[tid + 256] = keys[base + tid + 256];
  __syncthreads();
  unsigned long long kc = keys[cand];
  int c = 0;
#pragma unroll 8
  for (int t = 0; t < 512; ++t) c += (kk[t] < kc) ? 1 : 0;
  atomicAdd(&rank[cand], c);
}

__global__ void rank_place(const float* __restrict__ s, const int* __restrict__ rank, int k, int n,
                           int* __restrict__ kept, int* __restrict__ perm, float* __restrict__ vals) {
  int i = blockIdx.x * blockDim.x + threadIdx.x;
  if (i < n) {
    int r = rank[i];
    if (r < k) { perm[r] = i; vals[r] = s[i]; kept[i] = r; }
    else kept[i] = -1;
  }
}

__global__ void pool_gather(const float* __restrict__ X, const int* __restrict__ perm,
                            const float* __restrict__ vals, float* __restrict__ out, int C) {
  int a = blockIdx.x;
  int r = perm[a];
  float v = vals[a];
  for (int j = threadIdx.x; j < C; j += blockDim.x)
    out[(size_t)a * C + j] = X[(size_t)r * C + j] * v;
}

// ---------------- augment (sparse 2-path pairs) ----------------

__global__ void aug_pair(const int* __restrict__ csc_off, const int* __restrict__ csc_src,
                         const int* __restrict__ csr_off, const int* __restrict__ csr_dst,
                         const int* __restrict__ kept, float* __restrict__ Bp, int np) {
  int k = blockIdx.x;
  int is = csc_off[k], ni_e = csc_off[k + 1] - is;
  int os = csr_off[k], no_e = csr_off[k + 1] - os;
  int ni = ni_e + 1, no = no_e + 1;
  int tot = ni * no;
  for (int p = threadIdx.x; p < tot; p += blockDim.x) {
    int a = p / no, b = p - a * no;
    int i = (a < ni_e) ? csc_src[is + a] : k;
    int j = (b < no_e) ? csr_dst[os + b] : k;
    int ki = kept[i]; if (ki < 0) continue;
    int kj = kept[j]; if (kj < 0) continue;
    atomicAdd(&Bp[(size_t)ki * np + kj], 1.0f);
  }
}

__global__ void adddiag_kernel(float* __restrict__ B, int n) {
  int i = blockIdx.x * blockDim.x + threadIdx.x;
  if (i < n) B[(size_t)i * n + i] += 1.0f;
}

__global__ void colsum_part(const float* __restrict__ B, float* __restrict__ deg, int n, int rows_per) {
  int c = blockIdx.x * blockDim.x + threadIdx.x;
  int r0 = blockIdx.y * rows_per;
  float acc = 0.f;
  for (int r = r0; r < r0 + rows_per; ++r) acc += B[(size_t)r * n + c];
  atomicAdd(&deg[c], acc);
}

__global__ void dis_from_deg(const float* __restrict__ deg, float* __restrict__ dis, int n) {
  int i = blockIdx.x * blockDim.x + threadIdx.x;
  if (i < n) dis[i] = rsqrtf(deg[i]);
}

// ---------------- conversions ----------------

// fp32 row-major -> bf16 hi/lo row-major
__global__ void split_rm(const float* __restrict__ in, unsigned short* __restrict__ h,
                         unsigned short* __restrict__ l, int n) {
  int i = blockIdx.x * blockDim.x + threadIdx.x;
  if (i < n) { unsigned short hv, lv; split2(in[i], hv, lv); h[i] = hv; l[i] = lv; }
}

// fp32 row-major -> bf16 row-major (exact small ints)
__global__ void cvt_rm(const float* __restrict__ in, unsigned short* __restrict__ h, int n) {
  int i = blockIdx.x * blockDim.x + threadIdx.x;
  if (i < n) h[i] = bfbits((__bf16)in[i]);
}

// fp32 [R][C] -> bf16 hi/lo transposed [C][R]; ol may be null
__global__ __launch_bounds__(256) void tsplit(const float* __restrict__ in, unsigned short* __restrict__ oh,
                                              unsigned short* __restrict__ ol, int R, int C) {
  __shared__ float t[64][65];
  int r0 = blockIdx.y * 64, c0 = blockIdx.x * 64;
  int tid = threadIdx.x;
#pragma unroll
  for (int q = 0; q < 16; ++q) {
    int idx = q * 256 + tid;
    int rr = idx >> 6, cc = idx & 63;
    t[rr][cc] = in[(size_t)(r0 + rr) * C + c0 + cc];
  }
  __syncthreads();
#pragma unroll
  for (int q = 0; q < 16; ++q) {
    int idx = q * 256 + tid;
    int cc = idx >> 6, rr = idx & 63;
    float v = t[rr][cc];
    __bf16 hb = (__bf16)v;
    size_t o = (size_t)(c0 + cc) * R + r0 + rr;
    oh[o] = bfbits(hb);
    if (ol) ol[o] = bfbits((__bf16)(v - (float)hb));
  }
}

// ---------------- misc elementwise ----------------

__global__ void unpool_add(const float* __restrict__ res, const float* __restrict__ up,
                           const int* __restrict__ kept, float* __restrict__ out, int n, int C) {
  int idx = blockIdx.x * blockDim.x + threadIdx.x;
  if (idx < n * C) {
    int r = idx / C;
    int j = idx - r * C;
    int k = kept[r];
    float v = res[idx];
    if (k >= 0) v += up[(size_t)k * C + j];
    out[idx] = v;
  }
}

__global__ void spmm_gather(const float* __restrict__ Y, const int* __restrict__ off,
                            const int* __restrict__ srcs, const float* __restrict__ dis,
                            const float* __restrict__ bias, float* __restrict__ out, int C) {
  int c = blockIdx.x;
  int j = threadIdx.x;  // blockDim == C
  float acc = Y[(size_t)c * C + j];
  int s = off[c], e = off[c + 1];
  for (int t = s; t < e; ++t) acc += Y[(size_t)srcs[t] * C + j];
  out[(size_t)c * C + j] = fmaxf(dis[c] * acc + bias[j], 0.0f);
}

// ---------------- bf16-split MFMA GEMM ----------------
// C[i][j] = sum_k A[i][k] * B^T[j][k]  (A: M*K rm bf16 hi/lo; B: N*K rm (= B^T) bf16 hi/lo)
// optional row-gather permA/permB. Wave computes 32x32, block = 4 waves = 64x64 tile.
// EPI: 0 plain fp32; 1 rowscale fp32; 2 rowscale + transposed split bf16 out; 3 rowscale+bias+relu fp32
template <int EPI, int AL, int BL>
__global__ __launch_bounds__(256) void gemm16(
    const unsigned short* __restrict__ Ah, const unsigned short* __restrict__ Al,
    const unsigned short* __restrict__ Bh, const unsigned short* __restrict__ Bl,
    const int* __restrict__ permA, const int* __restrict__ permB,
    int M, int N, int K,
    const float* __restrict__ rs, const float* __restrict__ bias,
    float* __restrict__ C, unsigned short* __restrict__ Th, unsigned short* __restrict__ Tl) {
  const int wid = threadIdx.x >> 6, lane = threadIdx.x & 63;
  const int i0 = blockIdx.y * 64 + (wid >> 1) * 32;
  const int j0 = blockIdx.x * 64 + (wid & 1) * 32;
  const int lr = lane & 15, lk = lane >> 4;
  size_t aoff[2], boff[2];
#pragma unroll
  for (int t = 0; t < 2; ++t) {
    int ia = i0 + 16 * t + lr;
    int ra = permA ? permA[ia] : ia;
    aoff[t] = (size_t)ra * K + lk * 8;
    int jb = j0 + 16 * t + lr;
    int rb = permB ? permB[jb] : jb;
    boff[t] = (size_t)rb * K + lk * 8;
  }
  const f32x4 z = {0.f, 0.f, 0.f, 0.f};
  f32x4 acc[2][2];
  acc[0][0] = z; acc[0][1] = z; acc[1][0] = z; acc[1][1] = z;
  for (int k0 = 0; k0 < K; k0 += 32) {
    bf16x8 ah0 = *(const bf16x8*)(Ah + aoff[0] + k0);
    bf16x8 ah1 = *(const bf16x8*)(Ah + aoff[1] + k0);
    bf16x8 bh0 = *(const bf16x8*)(Bh + boff[0] + k0);
    bf16x8 bh1 = *(const bf16x8*)(Bh + boff[1] + k0);
    acc[0][0] = __builtin_amdgcn_mfma_f32_16x16x32_bf16(ah0, bh0, acc[0][0], 0, 0, 0);
    acc[0][1] = __builtin_amdgcn_mfma_f32_16x16x32_bf16(ah0, bh1, acc[0][1], 0, 0, 0);
    acc[1][0] = __builtin_amdgcn_mfma_f32_16x16x32_bf16(ah1, bh0, acc[1][0], 0, 0, 0);
    acc[1][1] = __builtin_amdgcn_mfma_f32_16x16x32_bf16(ah1, bh1, acc[1][1], 0, 0, 0);
    if constexpr (BL) {
      bf16x8 bl0 = *(const bf16x8*)(Bl + boff[0] + k0);
      bf16x8 bl1 = *(const bf16x8*)(Bl + boff[1] + k0);
      acc[0][0] = __builtin_amdgcn_mfma_f32_16x16x32_bf16(ah0, bl0, acc[0][0], 0, 0, 0);
      acc[0][1] = __builtin_amdgcn_mfma_f32_16x16x32_bf16(ah0, bl1, acc[0][1], 0, 0, 0);
      acc[1][0] = __builtin_amdgcn_mfma_f32_16x16x32_bf16(ah1, bl0, acc[1][0], 0, 0, 0);
      acc[1][1] = __builtin_amdgcn_mfma_f32_16x16x32_bf16(ah1, bl1, acc[1][1], 0, 0, 0);
    }
    if constexpr (AL) {
      bf16x8 al0 = *(const bf16x8*)(Al + aoff[0] + k0);
      bf16x8 al1 = *(const bf16x8*)(Al + aoff[1] + k0);
      acc[0][0] = __builtin_amdgcn_mfma_f32_16x16x32_bf16(al0, bh0, acc[0][0], 0, 0, 0);
      acc[0][1] = __builtin_amdgcn_mfma_f32_16x16x32_bf16(al0, bh1, acc[0][1], 0, 0, 0);
      acc[1][0] = __builtin_amdgcn_mfma_f32_16x16x32_bf16(al1, bh0, acc[1][0], 0, 0, 0);
      acc[1][1] = __builtin_amdgcn_mfma_f32_16x16x32_bf16(al1, bh1, acc[1][1], 0, 0, 0);
    }
  }
#pragma unroll
  for (int am = 0; am < 2; ++am)
#pragma unroll
    for (int bn = 0; bn < 2; ++bn) {
      int ib = i0 + 16 * am + lk * 4;
      int j = j0 + 16 * bn + lr;
      f32x4 a = acc[am][bn];
      if constexpr (EPI == 0) {
#pragma unroll
        for (int r = 0; r < 4; ++r) C[(size_t)(ib + r) * N + j] = a[r];
      } else if constexpr (EPI == 1) {
#pragma unroll
        for (int r = 0; r < 4; ++r) C[(size_t)(ib + r) * N + j] = rs[ib + r] * a[r];
      } else if constexpr (EPI == 2) {
        unsigned long long hp = 0, lp = 0;
#pragma unroll
        for (int r = 0; r < 4; ++r) {
          unsigned short hv, lv;
          split2(rs[ib + r] * a[r], hv, lv);
          hp |= ((unsigned long long)hv) << (16 * r);
          lp |= ((unsigned long long)lv) << (16 * r);
        }
        *(unsigned long long*)&Th[(size_t)j * M + ib] = hp;
        *(unsigned long long*)&Tl[(size_t)j * M + ib] = lp;
      } else {
#pragma unroll
        for (int r = 0; r < 4; ++r)
          C[(size_t)(ib + r) * N + j] = fmaxf(rs[ib + r] * a[r] + bias[j], 0.0f);
      }
    }
}

// ---------------- launch ----------------

extern "C" void kernel_launch(void* const* d_in, const int* in_sizes, int n_in,
                              void* d_out, int out_size, void* d_ws, size_t ws_size,
                              hipStream_t stream) {
  (void)in_sizes; (void)n_in; (void)out_size; (void)ws_size;
  const float* x  = (const float*)d_in[0];
  const int* ei   = (const int*)d_in[1];
  const int* esrc = ei;
  const int* edst = ei + EE;
  const float* w0 = (const float*)d_in[2];
  const float* b0 = (const float*)d_in[3];
  const float* w1 = (const float*)d_in[4];
  const float* b1 = (const float*)d_in[5];
  const float* w2 = (const float*)d_in[6];
  const float* b2 = (const float*)d_in[7];
  const float* w3 = (const float*)d_in[8];
  const float* b3 = (const float*)d_in[9];
  const float* w4 = (const float*)d_in[10];
  const float* b4 = (const float*)d_in[11];
  const float* p0 = (const float*)d_in[12];
  const float* p1 = (const float*)d_in[13];
  float* out = (float*)d_out;

  char* ws = (char*)d_ws;
  size_t off = 0;
  auto alloc = [&](size_t b) { void* p = ws + off; off += (b + 255) & ~(size_t)255; return p; };

  int* csc_off = (int*)alloc(4 * (NN + 1));
  int* csr_off = (int*)alloc(4 * (NN + 1));
  int* csc_src = (int*)alloc(4 * EE);
  int* csr_dst = (int*)alloc(4 * EE);

  // zeroed region: counts + degs + ranks
  size_t zero_bytes = 4 * NN * 4 + 4 * NP1 + 4 * NP2 + 4 * NN + 4 * NP1;
  int* cnts    = (int*)alloc(zero_bytes);
  int* cnt_dst = cnts;
  int* cnt_src = cnts + NN;
  int* fill_dst = cnts + 2 * NN;
  int* fill_src = cnts + 3 * NN;
  float* deg1 = (float*)(cnts + 4 * NN);
  float* deg2 = deg1 + NP1;
  int* rank0 = (int*)(deg2 + NP2);
  int* rank1 = rank0 + NN;

  int* kept0 = (int*)alloc(4 * NN);
  int* perm0 = (int*)alloc(4 * NP1);
  int* kept1 = (int*)alloc(4 * NP1);
  int* perm1 = (int*)alloc(4 * NP2);
  float* dis0 = (float*)alloc(4 * NN);
  float* dis1 = (float*)alloc(4 * NP1);
  float* dis2 = (float*)alloc(4 * NP2);
  float* pnrm = (float*)alloc(8);
  float* s0   = (float*)alloc(4 * NN);
  float* vals0 = (float*)alloc(4 * NP1);
  float* s1   = (float*)alloc(4 * NP1);
  float* vals1 = (float*)alloc(4 * NP2);
  unsigned long long* keys0 = (unsigned long long*)alloc(8 * NN);
  unsigned long long* keys1 = (unsigned long long*)alloc(8 * NP1);

  const size_t MB = 1024 * 1024;
  // B1 region (16MB): after B1 fp32 dies, hosts B2 / B2t splits / xin3 / xin4
  char* regB1 = (char*)alloc(16 * MB);
  float* B1   = (float*)regB1;                       // 2048^2 fp32, full 16MB
  float* B2   = (float*)regB1;                       // 1024^2 fp32 (4MB)  [after B1 dead]
  unsigned short* B2th = (unsigned short*)(regB1 + 4 * MB);   // 2MB
  unsigned short* B2tl = (unsigned short*)(regB1 + 6 * MB);   // 2MB
  float* xin3 = (float*)(regB1 + 8 * MB);            // 2048x512 fp32 (4MB)
  float* xin4 = (float*)(regB1 + 12 * MB);           // 4096x256 fp32 (4MB)

  unsigned short* B1rm = (unsigned short*)alloc(8 * MB);  // 2048^2 bf16 row-major (exact)
  unsigned short* B1t  = (unsigned short*)alloc(8 * MB);  // 2048^2 bf16 transposed (exact)
  float* res0 = (float*)alloc(4 * MB);   // 4096x256
  float* res1 = (float*)alloc(4 * MB);   // 2048x512
  float* yreg = (float*)alloc(4 * MB);   // y0 (4096x256) then y4 (4096x128)
  float* x1in = (float*)alloc(2 * MB);   // 2048x256, then x2in (1024x512)
  float* x2in = x1in;
  float* outreg = (float*)alloc(2 * MB); // out2 (1024x512) then out3 (2048x256)
  float* out2 = outreg, *out3 = outreg;
  char* ytreg = (char*)alloc(4 * MB);    // Y1t h+l (2+2MB) -> Y2t h+l (1+1) -> Y3t h+l (1+1)
  unsigned short* Y1th = (unsigned short*)ytreg;
  unsigned short* Y1tl = (unsigned short*)(ytreg + 2 * MB);
  unsigned short* Y2th = (unsigned short*)ytreg;
  unsigned short* Y2tl = (unsigned short*)(ytreg + 1 * MB);
  unsigned short* Y3th = (unsigned short*)ytreg;
  unsigned short* Y3tl = (unsigned short*)(ytreg + 1 * MB);
  char* xsreg = (char*)alloc(4 * MB);    // x3 h+l (2+2MB) -> x4 h+l (2+2MB)
  unsigned short* x3h = (unsigned short*)xsreg;
  unsigned short* x3l = (unsigned short*)(xsreg + 2 * MB);
  unsigned short* x4h = (unsigned short*)xsreg;
  unsigned short* x4l = (unsigned short*)(xsreg + 2 * MB);
  unsigned short* xh = (unsigned short*)alloc(1 * MB);   // 4096x128
  unsigned short* xl = (unsigned short*)alloc(1 * MB);
  char* xsm = (char*)alloc(2 * MB);      // x1 h+l (1+1MB) -> x2 h+l (1+1MB)
  unsigned short* x1h = (unsigned short*)xsm;
  unsigned short* x1l = (unsigned short*)(xsm + 1 * MB);
  unsigned short* x2h = (unsigned short*)xsm;
  unsigned short* x2l = (unsigned short*)(xsm + 1 * MB);
  // weights (transposed splits)
  unsigned short* Wt0h = (unsigned short*)alloc(256 * 128 * 2);
  unsigned short* Wt0l = (unsigned short*)alloc(256 * 128 * 2);
  unsigned short* Wt1h = (unsigned short*)alloc(512 * 256 * 2);
  unsigned short* Wt1l = (unsigned short*)alloc(512 * 256 * 2);
  unsigned short* Wt2h = (unsigned short*)alloc(512 * 512 * 2);
  unsigned short* Wt2l = (unsigned short*)alloc(512 * 512 * 2);
  unsigned short* Wt3h = (unsigned short*)alloc(256 * 512 * 2);
  unsigned short* Wt3l = (unsigned short*)alloc(256 * 512 * 2);
  unsigned short* Wt4h = (unsigned short*)alloc(128 * 256 * 2);
  unsigned short* Wt4l = (unsigned short*)alloc(128 * 256 * 2);

  hipMemsetAsync(cnts, 0, zero_bytes, stream);
  hipMemsetAsync(B1, 0, 16 * MB, stream);

  // graph build
  hist_kernel<<<EE / 256, 256, 0, stream>>>(esrc, edst, cnt_src, cnt_dst, EE);
  scan_kernel<<<1, 1024, 0, stream>>>(cnt_dst, csc_off, NN);
  scan_kernel<<<1, 1024, 0, stream>>>(cnt_src, csr_off, NN);
  scatter_kernel<<<EE / 256, 256, 0, stream>>>(esrc, edst, csc_off, csr_off,
                                               fill_dst, fill_src, csc_src, csr_dst, EE);
  dis0_kernel<<<NN / 256, 256, 0, stream>>>(cnt_dst, dis0, NN);
  pnorm_kernel<<<1, 256, 0, stream>>>(p0, pnrm + 0, 256);
  pnorm_kernel<<<1, 256, 0, stream>>>(p1, pnrm + 1, 512);

  // weight conversions
  tsplit<<<dim3(4, 2), 256, 0, stream>>>(w0, Wt0h, Wt0l, 128, 256);
  tsplit<<<dim3(8, 4), 256, 0, stream>>>(w1, Wt1h, Wt1l, 256, 512);
  tsplit<<<dim3(8, 8), 256, 0, stream>>>(w2, Wt2h, Wt2l, 512, 512);
  tsplit<<<dim3(4, 8), 256, 0, stream>>>(w3, Wt3h, Wt3l, 512, 256);
  tsplit<<<dim3(2, 4), 256, 0, stream>>>(w4, Wt4h, Wt4l, 256, 128);
  split_rm<<<(NN * 128) / 256, 256, 0, stream>>>(x, xh, xl, NN * 128);

  // gcn0
  gemm16<1, 1, 1><<<dim3(4, 64), 256, 0, stream>>>(xh, xl, Wt0h, Wt0l, nullptr, nullptr,
                                                   NN, 256, 128, dis0, nullptr, yreg, nullptr, nullptr);
  spmm_gather<<<NN, 256, 0, stream>>>(yreg, csc_off, csc_src, dis0, b0, res0, 256);

  // pool0
  score_kernel<<<NN, 256, 0, stream>>>(res0, p0, pnrm + 0, s0, 256);
  key_kernel<<<NN / 256, 256, 0, stream>>>(s0, keys0, NN);
  rank_count<<<dim3(NN / 256, NN / 512), 256, 0, stream>>>(keys0, rank0);
  rank_place<<<NN / 256, 256, 0, stream>>>(s0, rank0, NP1, NN, kept0, perm0, vals0);
  pool_gather<<<NP1, 256, 0, stream>>>(res0, perm0, vals0, x1in, 256);

  // augment0 -> B1 (+I), deg, dis; bf16 copies
  aug_pair<<<NN, 256, 0, stream>>>(csc_off, csc_src, csr_off, csr_dst, kept0, B1, NP1);
  adddiag_kernel<<<NP1 / 256, 256, 0, stream>>>(B1, NP1);
  colsum_part<<<dim3(NP1 / 256, NP1 / 256), 256, 0, stream>>>(B1, deg1, NP1, 256);
  dis_from_deg<<<NP1 / 256, 256, 0, stream>>>(deg1, dis1, NP1);
  cvt_rm<<<(NP1 * NP1) / 256, 256, 0, stream>>>(B1, B1rm, NP1 * NP1);
  tsplit<<<dim3(32, 32), 256, 0, stream>>>(B1, B1t, nullptr, NP1, NP1);
  split_rm<<<(NP1 * 256) / 256, 256, 0, stream>>>(x1in, x1h, x1l, NP1 * 256);
  // B1 fp32 dead from here on.

  // gcn1
  gemm16<2, 1, 1><<<dim3(8, 32), 256, 0, stream>>>(x1h, x1l, Wt1h, Wt1l, nullptr, nullptr,
                                                   NP1, 512, 256, dis1, nullptr, nullptr, Y1th, Y1tl);
  gemm16<3, 0, 1><<<dim3(8, 32), 256, 0, stream>>>(B1t, nullptr, Y1th, Y1tl, nullptr, nullptr,
                                                   NP1, 512, NP1, dis1, b1, res1, nullptr, nullptr);

  // pool1
  score_kernel<<<NP1, 256, 0, stream>>>(res1, p1, pnrm + 1, s1, 512);
  key_kernel<<<NP1 / 256, 256, 0, stream>>>(s1, keys1, NP1);
  rank_count<<<dim3(NP1 / 256, NP1 / 512), 256, 0, stream>>>(keys1, rank1);
  rank_place<<<NP1 / 256, 256, 0, stream>>>(s1, rank1, NP2, NP1, kept1, perm1, vals1);
  pool_gather<<<NP2, 256, 0, stream>>>(res1, perm1, vals1, x2in, 512);

  // augment1 (dense, exact bf16): B2 = B1[perm1,:] @ B1[:,perm1]
  gemm16<0, 0, 0><<<dim3(16, 16), 256, 0, stream>>>(B1rm, nullptr, B1t, nullptr, perm1, perm1,
                                                    NP2, NP2, NP1, nullptr, nullptr, B2, nullptr, nullptr);
  adddiag_kernel<<<NP2 / 256, 256, 0, stream>>>(B2, NP2);
  colsum_part<<<dim3(NP2 / 256, NP2 / 256), 256, 0, stream>>>(B2, deg2, NP2, 256);
  dis_from_deg<<<NP2 / 256, 256, 0, stream>>>(deg2, dis2, NP2);
  tsplit<<<dim3(16, 16), 256, 0, stream>>>(B2, B2th, B2tl, NP2, NP2);
  split_rm<<<(NP2 * 512) / 256, 256, 0, stream>>>(x2in, x2h, x2l, NP2 * 512);

  // gcn2 (bottleneck)
  gemm16<2, 1, 1><<<dim3(8, 16), 256, 0, stream>>>(x2h, x2l, Wt2h, Wt2l, nullptr, nullptr,
                                                   NP2, 512, 512, dis2, nullptr, nullptr, Y2th, Y2tl);
  gemm16<3, 1, 1><<<dim3(8, 16), 256, 0, stream>>>(B2th, B2tl, Y2th, Y2tl, nullptr, nullptr,
                                                   NP2, 512, NP2, dis2, b2, out2, nullptr, nullptr);

  // up1
  unpool_add<<<(NP1 * 512) / 256, 256, 0, stream>>>(res1, out2, kept1, xin3, NP1, 512);
  split_rm<<<(NP1 * 512) / 256, 256, 0, stream>>>(xin3, x3h, x3l, NP1 * 512);
  gemm16<2, 1, 1><<<dim3(4, 32), 256, 0, stream>>>(x3h, x3l, Wt3h, Wt3l, nullptr, nullptr,
                                                   NP1, 256, 512, dis1, nullptr, nullptr, Y3th, Y3tl);
  gemm16<3, 0, 1><<<dim3(4, 32), 256, 0, stream>>>(B1t, nullptr, Y3th, Y3tl, nullptr, nullptr,
                                                   NP1, 256, NP1, dis1, b3, out3, nullptr, nullptr);

  // up0
  unpool_add<<<(NN * 256) / 256, 256, 0, stream>>>(res0, out3, kept0, xin4, NN, 256);
  split_rm<<<(NN * 256) / 256, 256, 0, stream>>>(xin4, x4h, x4l, NN * 256);
  gemm16<1, 1, 1><<<dim3(2, 64), 256, 0, stream>>>(x4h, x4l, Wt4h, Wt4l, nullptr, nullptr,
                                                   NN, 128, 256, dis0, nullptr, yreg, nullptr, nullptr);
  spmm_gather<<<NN, 128, 0, stream>>>(yreg, csc_off, csc_src, dis0, b4, out, 128);
}

// Round 3
// 508.729 us; speedup vs baseline: 2.1165x; 1.2372x over previous
//
#include <hip/hip_runtime.h>

#define NN 4096
#define EE 131072
#define NP1 2048
#define NP2 1024

typedef __attribute__((ext_vector_type(8))) __bf16 bf16x8;
typedef __attribute__((ext_vector_type(4))) float f32x4;

static __device__ inline unsigned short bfbits(__bf16 b) {
  union { __bf16 x; unsigned short u; } c; c.x = b; return c.u;
}
static __device__ inline void split2(float v, unsigned short& h, unsigned short& l) {
  __bf16 hb = (__bf16)v;
  float hf = (float)hb;
  __bf16 lb = (__bf16)(v - hf);
  h = bfbits(hb); l = bfbits(lb);
}

// ---------------- graph build ----------------

__global__ void hist_kernel(const int* __restrict__ src, const int* __restrict__ dst,
                            int* __restrict__ cnt_src, int* __restrict__ cnt_dst, int E) {
  int e = blockIdx.x * blockDim.x + threadIdx.x;
  if (e < E) {
    atomicAdd(&cnt_src[src[e]], 1);
    atomicAdd(&cnt_dst[dst[e]], 1);
  }
}

__global__ __launch_bounds__(1024) void scan_kernel(const int* __restrict__ in, int* __restrict__ out, int n) {
  __shared__ int tmp[4096];
  int tid = threadIdx.x;
  for (int i = tid; i < n; i += 1024) tmp[i] = in[i];
  __syncthreads();
  for (int off = 1; off < n; off <<= 1) {
    int v[4];
    int c = 0;
    for (int i = tid; i < n; i += 1024) { v[c++] = (i >= off) ? tmp[i - off] : 0; }
    __syncthreads();
    c = 0;
    for (int i = tid; i < n; i += 1024) { tmp[i] += v[c++]; }
    __syncthreads();
  }
  for (int i = tid; i < n; i += 1024) out[i + 1] = tmp[i];
  if (tid == 0) out[0] = 0;
}

__global__ void scatter_kernel(const int* __restrict__ src, const int* __restrict__ dst,
                               const int* __restrict__ csc_off, const int* __restrict__ csr_off,
                               int* __restrict__ fill_dst, int* __restrict__ fill_src,
                               int* __restrict__ csc_src, int* __restrict__ csr_dst, int E) {
  int e = blockIdx.x * blockDim.x + threadIdx.x;
  if (e < E) {
    int s = src[e], d = dst[e];
    int p = atomicAdd(&fill_dst[d], 1);
    csc_src[csc_off[d] + p] = s;
    int q = atomicAdd(&fill_src[s], 1);
    csr_dst[csr_off[s] + q] = d;
  }
}

__global__ void dis0_kernel(const int* __restrict__ cnt_dst, float* __restrict__ dis, int n) {
  int i = blockIdx.x * blockDim.x + threadIdx.x;
  if (i < n) dis[i] = rsqrtf((float)cnt_dst[i] + 1.0f);
}

__global__ void pnorm_kernel(const float* __restrict__ p, float* __restrict__ outv, int C) {
  int tid = threadIdx.x;
  float acc = 0.f;
  for (int j = tid; j < C; j += 256) { float v = p[j]; acc += v * v; }
  for (int o = 32; o > 0; o >>= 1) acc += __shfl_down(acc, o);
  __shared__ float red[4];
  if ((tid & 63) == 0) red[tid >> 6] = acc;
  __syncthreads();
  if (tid == 0) outv[0] = sqrtf(red[0] + red[1] + red[2] + red[3]);
}

// ---------------- scoring / topk ----------------

__global__ void score_kernel(const float* __restrict__ X, const float* __restrict__ p,
                             const float* __restrict__ pn, float* __restrict__ s, int C) {
  int i = blockIdx.x;
  int tid = threadIdx.x;
  float acc = 0.f;
  for (int j = tid; j < C; j += 256) acc += X[(size_t)i * C + j] * p[j];
  for (int o = 32; o > 0; o >>= 1) acc += __shfl_down(acc, o);
  __shared__ float red[4];
  if ((tid & 63) == 0) red[tid >> 6] = acc;
  __syncthreads();
  if (tid == 0) s[i] = tanhf((red[0] + red[1] + red[2] + red[3]) / pn[0]);
}

__global__ void key_kernel(const float* __restrict__ s, unsigned long long* __restrict__ keys, int n) {
  int i = blockIdx.x * blockDim.x + threadIdx.x;
  if (i < n) {
    unsigned u = __float_as_uint(s[i]);
    unsigned m = (u & 0x80000000u) ? ~u : (u | 0x80000000u);
    keys[i] = (((unsigned long long)(~m)) << 32) | (unsigned)i;  // desc value, asc index
  }
}

__global__ __launch_bounds__(256) void rank_count(const unsigned long long* __restrict__ keys,
                                                  int* __restrict__ rank) {
  __shared__ unsigned long long kk[512];
  int tid = threadIdx.x;
  int cand = blockIdx.x * 256 + tid;
  int base = blockIdx.y * 512;
  kk[tid] = keys[base + tid];
  kk[tid + 256] = keys[base + tid + 256];
  __syncthreads();
  unsigned long long kc = keys[cand];
  int c = 0;
#pragma unroll 8
  for (int t = 0; t < 512; ++t) c += (kk[t] < kc) ? 1 : 0;
  atomicAdd(&rank[cand], c);
}

__global__ void rank_place(const float* __restrict__ s, const int* __restrict__ rank, int k, int n,
                           int* __restrict__ kept, int* __restrict__ perm, float* __restrict__ vals) {
  int i = blockIdx.x * blockDim.x + threadIdx.x;
  if (i < n) {
    int r = rank[i];
    if (r < k) { perm[r] = i; vals[r] = s[i]; kept[i] = r; }
    else kept[i] = -1;
  }
}

__global__ void pool_gather(const float* __restrict__ X, const int* __restrict__ perm,
                            const float* __restrict__ vals, float* __restrict__ out, int C) {
  int a = blockIdx.x;
  int r = perm[a];
  float v = vals[a];
  for (int j = threadIdx.x; j < C; j += blockDim.x)
    out[(size_t)a * C + j] = X[(size_t)r * C + j] * v;
}

// ---------------- augment (sparse 2-path pairs) ----------------

__global__ void aug_pair(const int* __restrict__ csc_off, const int* __restrict__ csc_src,
                         const int* __restrict__ csr_off, const int* __restrict__ csr_dst,
                         const int* __restrict__ kept, float* __restrict__ Bp, int np) {
  int k = blockIdx.x;
  int is = csc_off[k], ni_e = csc_off[k + 1] - is;
  int os = csr_off[k], no_e = csr_off[k + 1] - os;
  int ni = ni_e + 1, no = no_e + 1;
  int tot = ni * no;
  for (int p = threadIdx.x; p < tot; p += blockDim.x) {
    int a = p / no, b = p - a * no;
    int i = (a < ni_e) ? csc_src[is + a] : k;
    int j = (b < no_e) ? csr_dst[os + b] : k;
    int ki = kept[i]; if (ki < 0) continue;
    int kj = kept[j]; if (kj < 0) continue;
    atomicAdd(&Bp[(size_t)ki * np + kj], 1.0f);
  }
}

__global__ void adddiag_kernel(float* __restrict__ B, int n) {
  int i = blockIdx.x * blockDim.x + threadIdx.x;
  if (i < n) B[(size_t)i * n + i] += 1.0f;
}

// rows_per = 16: high occupancy, short serial chains
__global__ void colsum_part(const float* __restrict__ B, float* __restrict__ deg, int n) {
  int c = blockIdx.x * blockDim.x + threadIdx.x;
  int r0 = blockIdx.y * 16;
  float acc = 0.f;
#pragma unroll
  for (int r = 0; r < 16; ++r) acc += B[(size_t)(r0 + r) * n + c];
  atomicAdd(&deg[c], acc);
}

__global__ void dis_from_deg(const float* __restrict__ deg, float* __restrict__ dis, int n) {
  int i = blockIdx.x * blockDim.x + threadIdx.x;
  if (i < n) dis[i] = rsqrtf(deg[i]);
}

// ---------------- conversions ----------------

// fp32 row-major -> bf16 hi/lo row-major
__global__ void split_rm(const float* __restrict__ in, unsigned short* __restrict__ h,
                         unsigned short* __restrict__ l, int n) {
  int i = blockIdx.x * blockDim.x + threadIdx.x;
  if (i < n) { unsigned short hv, lv; split2(in[i], hv, lv); h[i] = hv; l[i] = lv; }
}

// B1 fp32 -> bf16 row-major AND bf16 transposed (exact small ints), single pass
__global__ __launch_bounds__(256) void b1_dual(const float* __restrict__ in,
                                               unsigned short* __restrict__ rm,
                                               unsigned short* __restrict__ tr, int n) {
  __shared__ float t[64][65];
  int r0 = blockIdx.y * 64, c0 = blockIdx.x * 64;
  int tid = threadIdx.x;
#pragma unroll
  for (int q = 0; q < 16; ++q) {
    int idx = q * 256 + tid;
    int rr = idx >> 6, cc = idx & 63;
    float v = in[(size_t)(r0 + rr) * n + c0 + cc];
    t[rr][cc] = v;
    rm[(size_t)(r0 + rr) * n + c0 + cc] = bfbits((__bf16)v);
  }
  __syncthreads();
#pragma unroll
  for (int q = 0; q < 16; ++q) {
    int idx = q * 256 + tid;
    int cc = idx >> 6, rr = idx & 63;
    tr[(size_t)(c0 + cc) * n + r0 + rr] = bfbits((__bf16)t[rr][cc]);
  }
}

// fp32 [R][C] -> bf16 hi/lo transposed [C][R]; ol may be null
__global__ __launch_bounds__(256) void tsplit(const float* __restrict__ in, unsigned short* __restrict__ oh,
                                              unsigned short* __restrict__ ol, int R, int C) {
  __shared__ float t[64][65];
  int r0 = blockIdx.y * 64, c0 = blockIdx.x * 64;
  int tid = threadIdx.x;
#pragma unroll
  for (int q = 0; q < 16; ++q) {
    int idx = q * 256 + tid;
    int rr = idx >> 6, cc = idx & 63;
    t[rr][cc] = in[(size_t)(r0 + rr) * C + c0 + cc];
  }
  __syncthreads();
#pragma unroll
  for (int q = 0; q < 16; ++q) {
    int idx = q * 256 + tid;
    int cc = idx >> 6, rr = idx & 63;
    float v = t[rr][cc];
    __bf16 hb = (__bf16)v;
    size_t o = (size_t)(c0 + cc) * R + r0 + rr;
    oh[o] = bfbits(hb);
    if (ol) ol[o] = bfbits((__bf16)(v - (float)hb));
  }
}

// ---------------- misc elementwise ----------------

__global__ void unpool_add(const float* __restrict__ res, const float* __restrict__ up,
                           const int* __restrict__ kept, float* __restrict__ out, int n, int C) {
  int idx = blockIdx.x * blockDim.x + threadIdx.x;
  if (idx < n * C) {
    int r = idx / C;
    int j = idx - r * C;
    int k = kept[r];
    float v = res[idx];
    if (k >= 0) v += up[(size_t)k * C + j];
    out[idx] = v;
  }
}

// wave-per-row vectorized SpMM gather: 4 rows/block, 64 lanes * VEC floats
template <int C>
__global__ __launch_bounds__(256) void spmm_gather_v(const float* __restrict__ Y,
                                                     const int* __restrict__ off,
                                                     const int* __restrict__ srcs,
                                                     const float* __restrict__ dis,
                                                     const float* __restrict__ bias,
                                                     float* __restrict__ out) {
  constexpr int VEC = C / 64;
  int w = threadIdx.x >> 6, lane = threadIdx.x & 63;
  int c = blockIdx.x * 4 + w;
  int j = lane * VEC;
  float acc[VEC];
  const float* p = Y + (size_t)c * C + j;
#pragma unroll
  for (int u = 0; u < VEC; ++u) acc[u] = p[u];
  int s = off[c], e = off[c + 1];
  for (int t = s; t < e; ++t) {
    const float* q = Y + (size_t)srcs[t] * C + j;
#pragma unroll
    for (int u = 0; u < VEC; ++u) acc[u] += q[u];
  }
  float d = dis[c];
  float* o = out + (size_t)c * C + j;
#pragma unroll
  for (int u = 0; u < VEC; ++u) o[u] = fmaxf(d * acc[u] + bias[j + u], 0.0f);
}

// ---------------- bf16-split MFMA GEMM ----------------
// C[i][j] = sum_k A[i][k] * B^T[j][k]  (A: M*K rm bf16 hi/lo; B: N*K rm (= B^T) bf16 hi/lo)
// optional row-gather permA/permB. Wave computes 32x32, block = 4 waves = 64x64 tile.
// K compile-time: full unroll + register double-buffer prefetch.
// EPI: 0 plain fp32; 1 rowscale fp32; 2 rowscale + transposed split bf16 out; 3 rowscale+bias+relu fp32
template <int EPI, int AL, int BL, int K>
__global__ __launch_bounds__(256) void gemm16(
    const unsigned short* __restrict__ Ah, const unsigned short* __restrict__ Al,
    const unsigned short* __restrict__ Bh, const unsigned short* __restrict__ Bl,
    const int* __restrict__ permA, const int* __restrict__ permB,
    int M, int N,
    const float* __restrict__ rs, const float* __restrict__ bias,
    float* __restrict__ C, unsigned short* __restrict__ Th, unsigned short* __restrict__ Tl) {
  static_assert(K % 32 == 0, "K");
  const int wid = threadIdx.x >> 6, lane = threadIdx.x & 63;
  const int i0 = blockIdx.y * 64 + (wid >> 1) * 32;
  const int j0 = blockIdx.x * 64 + (wid & 1) * 32;
  const int lr = lane & 15, lk = lane >> 4;
  size_t aoff[2], boff[2];
#pragma unroll
  for (int t = 0; t < 2; ++t) {
    int ia = i0 + 16 * t + lr;
    int ra = permA ? permA[ia] : ia;
    aoff[t] = (size_t)ra * K + lk * 8;
    int jb = j0 + 16 * t + lr;
    int rb = permB ? permB[jb] : jb;
    boff[t] = (size_t)rb * K + lk * 8;
  }
  const f32x4 z = {0.f, 0.f, 0.f, 0.f};
  f32x4 acc[2][2];
  acc[0][0] = z; acc[0][1] = z; acc[1][0] = z; acc[1][1] = z;

  bf16x8 ahf[2][2], bhf[2][2], alf[2][2], blf[2][2];
  auto loadk = [&](int k0, int b) {
    ahf[b][0] = *(const bf16x8*)(Ah + aoff[0] + k0);
    ahf[b][1] = *(const bf16x8*)(Ah + aoff[1] + k0);
    bhf[b][0] = *(const bf16x8*)(Bh + boff[0] + k0);
    bhf[b][1] = *(const bf16x8*)(Bh + boff[1] + k0);
    if constexpr (AL) {
      alf[b][0] = *(const bf16x8*)(Al + aoff[0] + k0);
      alf[b][1] = *(const bf16x8*)(Al + aoff[1] + k0);
    }
    if constexpr (BL) {
      blf[b][0] = *(const bf16x8*)(Bl + boff[0] + k0);
      blf[b][1] = *(const bf16x8*)(Bl + boff[1] + k0);
    }
  };
  auto domm = [&](int b) {
#pragma unroll
    for (int am = 0; am < 2; ++am)
#pragma unroll
      for (int bn = 0; bn < 2; ++bn) {
        acc[am][bn] = __builtin_amdgcn_mfma_f32_16x16x32_bf16(ahf[b][am], bhf[b][bn], acc[am][bn], 0, 0, 0);
        if constexpr (BL)
          acc[am][bn] = __builtin_amdgcn_mfma_f32_16x16x32_bf16(ahf[b][am], blf[b][bn], acc[am][bn], 0, 0, 0);
        if constexpr (AL)
          acc[am][bn] = __builtin_amdgcn_mfma_f32_16x16x32_bf16(alf[b][am], bhf[b][bn], acc[am][bn], 0, 0, 0);
      }
  };

  loadk(0, 0);
#pragma unroll
  for (int k0 = 0; k0 < K; k0 += 32) {
    const int cur = (k0 >> 5) & 1;
    if (k0 + 32 < K) loadk(k0 + 32, cur ^ 1);
    domm(cur);
  }

#pragma unroll
  for (int am = 0; am < 2; ++am)
#pragma unroll
    for (int bn = 0; bn < 2; ++bn) {
      int ib = i0 + 16 * am + lk * 4;
      int j = j0 + 16 * bn + lr;
      f32x4 a = acc[am][bn];
      if constexpr (EPI == 0) {
#pragma unroll
        for (int r = 0; r < 4; ++r) C[(size_t)(ib + r) * N + j] = a[r];
      } else if constexpr (EPI == 1) {
#pragma unroll
        for (int r = 0; r < 4; ++r) C[(size_t)(ib + r) * N + j] = rs[ib + r] * a[r];
      } else if constexpr (EPI == 2) {
        unsigned long long hp = 0, lp = 0;
#pragma unroll
        for (int r = 0; r < 4; ++r) {
          unsigned short hv, lv;
          split2(rs[ib + r] * a[r], hv, lv);
          hp |= ((unsigned long long)hv) << (16 * r);
          lp |= ((unsigned long long)lv) << (16 * r);
        }
        *(unsigned long long*)&Th[(size_t)j * M + ib] = hp;
        *(unsigned long long*)&Tl[(size_t)j * M + ib] = lp;
      } else {
#pragma unroll
        for (int r = 0; r < 4; ++r)
          C[(size_t)(ib + r) * N + j] = fmaxf(rs[ib + r] * a[r] + bias[j], 0.0f);
      }
    }
}

// ---------------- launch ----------------

extern "C" void kernel_launch(void* const* d_in, const int* in_sizes, int n_in,
                              void* d_out, int out_size, void* d_ws, size_t ws_size,
                              hipStream_t stream) {
  (void)in_sizes; (void)n_in; (void)out_size; (void)ws_size;
  const float* x  = (const float*)d_in[0];
  const int* ei   = (const int*)d_in[1];
  const int* esrc = ei;
  const int* edst = ei + EE;
  const float* w0 = (const float*)d_in[2];
  const float* b0 = (const float*)d_in[3];
  const float* w1 = (const float*)d_in[4];
  const float* b1 = (const float*)d_in[5];
  const float* w2 = (const float*)d_in[6];
  const float* b2 = (const float*)d_in[7];
  const float* w3 = (const float*)d_in[8];
  const float* b3 = (const float*)d_in[9];
  const float* w4 = (const float*)d_in[10];
  const float* b4 = (const float*)d_in[11];
  const float* p0 = (const float*)d_in[12];
  const float* p1 = (const float*)d_in[13];
  float* out = (float*)d_out;

  char* ws = (char*)d_ws;
  size_t off = 0;
  auto alloc = [&](size_t b) { void* p = ws + off; off += (b + 255) & ~(size_t)255; return p; };

  int* csc_off = (int*)alloc(4 * (NN + 1));
  int* csr_off = (int*)alloc(4 * (NN + 1));
  int* csc_src = (int*)alloc(4 * EE);
  int* csr_dst = (int*)alloc(4 * EE);

  // zeroed region: counts + degs + ranks
  size_t zero_bytes = 4 * NN * 4 + 4 * NP1 + 4 * NP2 + 4 * NN + 4 * NP1;
  int* cnts    = (int*)alloc(zero_bytes);
  int* cnt_dst = cnts;
  int* cnt_src = cnts + NN;
  int* fill_dst = cnts + 2 * NN;
  int* fill_src = cnts + 3 * NN;
  float* deg1 = (float*)(cnts + 4 * NN);
  float* deg2 = deg1 + NP1;
  int* rank0 = (int*)(deg2 + NP2);
  int* rank1 = rank0 + NN;

  int* kept0 = (int*)alloc(4 * NN);
  int* perm0 = (int*)alloc(4 * NP1);
  int* kept1 = (int*)alloc(4 * NP1);
  int* perm1 = (int*)alloc(4 * NP2);
  float* dis0 = (float*)alloc(4 * NN);
  float* dis1 = (float*)alloc(4 * NP1);
  float* dis2 = (float*)alloc(4 * NP2);
  float* pnrm = (float*)alloc(8);
  float* s0   = (float*)alloc(4 * NN);
  float* vals0 = (float*)alloc(4 * NP1);
  float* s1   = (float*)alloc(4 * NP1);
  float* vals1 = (float*)alloc(4 * NP2);
  unsigned long long* keys0 = (unsigned long long*)alloc(8 * NN);
  unsigned long long* keys1 = (unsigned long long*)alloc(8 * NP1);

  const size_t MB = 1024 * 1024;
  // B1 region (16MB): after B1 fp32 dies, hosts B2 / B2t splits / xin3 / xin4
  char* regB1 = (char*)alloc(16 * MB);
  float* B1   = (float*)regB1;                       // 2048^2 fp32, full 16MB
  float* B2   = (float*)regB1;                       // 1024^2 fp32 (4MB)  [after B1 dead]
  unsigned short* B2th = (unsigned short*)(regB1 + 4 * MB);   // 2MB
  unsigned short* B2tl = (unsigned short*)(regB1 + 6 * MB);   // 2MB
  float* xin3 = (float*)(regB1 + 8 * MB);            // 2048x512 fp32 (4MB)
  float* xin4 = (float*)(regB1 + 12 * MB);           // 4096x256 fp32 (4MB)

  unsigned short* B1rm = (unsigned short*)alloc(8 * MB);  // 2048^2 bf16 row-major (exact)
  unsigned short* B1t  = (unsigned short*)alloc(8 * MB);  // 2048^2 bf16 transposed (exact)
  float* res0 = (float*)alloc(4 * MB);   // 4096x256
  float* res1 = (float*)alloc(4 * MB);   // 2048x512
  float* yreg = (float*)alloc(4 * MB);   // y0 (4096x256) then y4 (4096x128)
  float* x1in = (float*)alloc(2 * MB);   // 2048x256, then x2in (1024x512)
  float* x2in = x1in;
  float* outreg = (float*)alloc(2 * MB); // out2 (1024x512) then out3 (2048x256)
  float* out2 = outreg, *out3 = outreg;
  char* ytreg = (char*)alloc(4 * MB);    // Y1t h+l (2+2MB) -> Y2t h+l (1+1) -> Y3t h+l (1+1)
  unsigned short* Y1th = (unsigned short*)ytreg;
  unsigned short* Y1tl = (unsigned short*)(ytreg + 2 * MB);
  unsigned short* Y2th = (unsigned short*)ytreg;
  unsigned short* Y2tl = (unsigned short*)(ytreg + 1 * MB);
  unsigned short* Y3th = (unsigned short*)ytreg;
  unsigned short* Y3tl = (unsigned short*)(ytreg + 1 * MB);
  char* xsreg = (char*)alloc(4 * MB);    // x3 h+l (2+2MB) -> x4 h+l (2+2MB)
  unsigned short* x3h = (unsigned short*)xsreg;
  unsigned short* x3l = (unsigned short*)(xsreg + 2 * MB);
  unsigned short* x4h = (unsigned short*)xsreg;
  unsigned short* x4l = (unsigned short*)(xsreg + 2 * MB);
  unsigned short* xh = (unsigned short*)alloc(1 * MB);   // 4096x128
  unsigned short* xl = (unsigned short*)alloc(1 * MB);
  char* xsm = (char*)alloc(2 * MB);      // x1 h+l (1+1MB) -> x2 h+l (1+1MB)
  unsigned short* x1h = (unsigned short*)xsm;
  unsigned short* x1l = (unsigned short*)(xsm + 1 * MB);
  unsigned short* x2h = (unsigned short*)xsm;
  unsigned short* x2l = (unsigned short*)(xsm + 1 * MB);
  // weights (transposed splits)
  unsigned short* Wt0h = (unsigned short*)alloc(256 * 128 * 2);
  unsigned short* Wt0l = (unsigned short*)alloc(256 * 128 * 2);
  unsigned short* Wt1h = (unsigned short*)alloc(512 * 256 * 2);
  unsigned short* Wt1l = (unsigned short*)alloc(512 * 256 * 2);
  unsigned short* Wt2h = (unsigned short*)alloc(512 * 512 * 2);
  unsigned short* Wt2l = (unsigned short*)alloc(512 * 512 * 2);
  unsigned short* Wt3h = (unsigned short*)alloc(256 * 512 * 2);
  unsigned short* Wt3l = (unsigned short*)alloc(256 * 512 * 2);
  unsigned short* Wt4h = (unsigned short*)alloc(128 * 256 * 2);
  unsigned short* Wt4l = (unsigned short*)alloc(128 * 256 * 2);

  hipMemsetAsync(cnts, 0, zero_bytes, stream);
  hipMemsetAsync(B1, 0, 16 * MB, stream);

  // graph build
  hist_kernel<<<EE / 256, 256, 0, stream>>>(esrc, edst, cnt_src, cnt_dst, EE);
  scan_kernel<<<1, 1024, 0, stream>>>(cnt_dst, csc_off, NN);
  scan_kernel<<<1, 1024, 0, stream>>>(cnt_src, csr_off, NN);
  scatter_kernel<<<EE / 256, 256, 0, stream>>>(esrc, edst, csc_off, csr_off,
                                               fill_dst, fill_src, csc_src, csr_dst, EE);
  dis0_kernel<<<NN / 256, 256, 0, stream>>>(cnt_dst, dis0, NN);
  pnorm_kernel<<<1, 256, 0, stream>>>(p0, pnrm + 0, 256);
  pnorm_kernel<<<1, 256, 0, stream>>>(p1, pnrm + 1, 512);

  // weight conversions
  tsplit<<<dim3(4, 2), 256, 0, stream>>>(w0, Wt0h, Wt0l, 128, 256);
  tsplit<<<dim3(8, 4), 256, 0, stream>>>(w1, Wt1h, Wt1l, 256, 512);
  tsplit<<<dim3(8, 8), 256, 0, stream>>>(w2, Wt2h, Wt2l, 512, 512);
  tsplit<<<dim3(4, 8), 256, 0, stream>>>(w3, Wt3h, Wt3l, 512, 256);
  tsplit<<<dim3(2, 4), 256, 0, stream>>>(w4, Wt4h, Wt4l, 256, 128);
  split_rm<<<(NN * 128) / 256, 256, 0, stream>>>(x, xh, xl, NN * 128);

  // gcn0
  gemm16<1, 1, 1, 128><<<dim3(4, 64), 256, 0, stream>>>(xh, xl, Wt0h, Wt0l, nullptr, nullptr,
                                                        NN, 256, dis0, nullptr, yreg, nullptr, nullptr);
  spmm_gather_v<256><<<NN / 4, 256, 0, stream>>>(yreg, csc_off, csc_src, dis0, b0, res0);

  // pool0
  score_kernel<<<NN, 256, 0, stream>>>(res0, p0, pnrm + 0, s0, 256);
  key_kernel<<<NN / 256, 256, 0, stream>>>(s0, keys0, NN);
  rank_count<<<dim3(NN / 256, NN / 512), 256, 0, stream>>>(keys0, rank0);
  rank_place<<<NN / 256, 256, 0, stream>>>(s0, rank0, NP1, NN, kept0, perm0, vals0);
  pool_gather<<<NP1, 256, 0, stream>>>(res0, perm0, vals0, x1in, 256);

  // augment0 -> B1 (+I), deg, dis; bf16 copies
  aug_pair<<<NN, 256, 0, stream>>>(csc_off, csc_src, csr_off, csr_dst, kept0, B1, NP1);
  adddiag_kernel<<<NP1 / 256, 256, 0, stream>>>(B1, NP1);
  colsum_part<<<dim3(NP1 / 256, NP1 / 16), 256, 0, stream>>>(B1, deg1, NP1);
  dis_from_deg<<<NP1 / 256, 256, 0, stream>>>(deg1, dis1, NP1);
  b1_dual<<<dim3(32, 32), 256, 0, stream>>>(B1, B1rm, B1t, NP1);
  split_rm<<<(NP1 * 256) / 256, 256, 0, stream>>>(x1in, x1h, x1l, NP1 * 256);
  // B1 fp32 dead from here on.

  // gcn1
  gemm16<2, 1, 1, 256><<<dim3(8, 32), 256, 0, stream>>>(x1h, x1l, Wt1h, Wt1l, nullptr, nullptr,
                                                        NP1, 512, dis1, nullptr, nullptr, Y1th, Y1tl);
  gemm16<3, 0, 1, 2048><<<dim3(8, 32), 256, 0, stream>>>(B1t, nullptr, Y1th, Y1tl, nullptr, nullptr,
                                                         NP1, 512, dis1, b1, res1, nullptr, nullptr);

  // pool1
  score_kernel<<<NP1, 256, 0, stream>>>(res1, p1, pnrm + 1, s1, 512);
  key_kernel<<<NP1 / 256, 256, 0, stream>>>(s1, keys1, NP1);
  rank_count<<<dim3(NP1 / 256, NP1 / 512), 256, 0, stream>>>(keys1, rank1);
  rank_place<<<NP1 / 256, 256, 0, stream>>>(s1, rank1, NP2, NP1, kept1, perm1, vals1);
  pool_gather<<<NP2, 256, 0, stream>>>(res1, perm1, vals1, x2in, 512);

  // augment1 (dense, exact bf16): B2 = B1[perm1,:] @ B1[:,perm1]
  gemm16<0, 0, 0, 2048><<<dim3(16, 16), 256, 0, stream>>>(B1rm, nullptr, B1t, nullptr, perm1, perm1,
                                                          NP2, NP2, nullptr, nullptr, B2, nullptr, nullptr);
  adddiag_kernel<<<NP2 / 256, 256, 0, stream>>>(B2, NP2);
  colsum_part<<<dim3(NP2 / 256, NP2 / 16), 256, 0, stream>>>(B2, deg2, NP2);
  dis_from_deg<<<NP2 / 256, 256, 0, stream>>>(deg2, dis2, NP2);
  tsplit<<<dim3(16, 16), 256, 0, stream>>>(B2, B2th, B2tl, NP2, NP2);
  split_rm<<<(NP2 * 512) / 256, 256, 0, stream>>>(x2in, x2h, x2l, NP2 * 512);

  // gcn2 (bottleneck)
  gemm16<2, 1, 1, 512><<<dim3(8, 16), 256, 0, stream>>>(x2h, x2l, Wt2h, Wt2l, nullptr, nullptr,
                                                        NP2, 512, dis2, nullptr, nullptr, Y2th, Y2tl);
  gemm16<3, 1, 1, 1024><<<dim3(8, 16), 256, 0, stream>>>(B2th, B2tl, Y2th, Y2tl, nullptr, nullptr,
                                                         NP2, 512, dis2, b2, out2, nullptr, nullptr);

  // up1
  unpool_add<<<(NP1 * 512) / 256, 256, 0, stream>>>(res1, out2, kept1, xin3, NP1, 512);
  split_rm<<<(NP1 * 512) / 256, 256, 0, stream>>>(xin3, x3h, x3l, NP1 * 512);
  gemm16<2, 1, 1, 512><<<dim3(4, 32), 256, 0, stream>>>(x3h, x3l, Wt3h, Wt3l, nullptr, nullptr,
                                                        NP1, 256, dis1, nullptr, nullptr, Y3th, Y3tl);
  gemm16<3, 0, 1, 2048><<<dim3(4, 32), 256, 0, stream>>>(B1t, nullptr, Y3th, Y3tl, nullptr, nullptr,
                                                         NP1, 256, dis1, b3, out3, nullptr, nullptr);

  // up0
  unpool_add<<<(NN * 256) / 256, 256, 0, stream>>>(res0, out3, kept0, xin4, NN, 256);
  split_rm<<<(NN * 256) / 256, 256, 0, stream>>>(xin4, x4h, x4l, NN * 256);
  gemm16<1, 1, 1, 256><<<dim3(2, 64), 256, 0, stream>>>(x4h, x4l, Wt4h, Wt4l, nullptr, nullptr,
                                                        NN, 128, dis0, nullptr, yreg, nullptr, nullptr);
  spmm_gather_v<128><<<NN / 4, 256, 0, stream>>>(yreg, csc_off, csc_src, dis0, b4, out);
}

// Round 4
// 446.508 us; speedup vs baseline: 2.4115x; 1.1394x over previous
//
#include <hip/hip_runtime.h>

#define NN 4096
#define EE 131072
#define NP1 2048
#define NP2 1024

typedef __attribute__((ext_vector_type(8))) __bf16 bf16x8;
typedef __attribute__((ext_vector_type(4))) float f32x4;

static __device__ inline unsigned short bfbits(__bf16 b) {
  union { __bf16 x; unsigned short u; } c; c.x = b; return c.u;
}
static __device__ inline void split2(float v, unsigned short& h, unsigned short& l) {
  __bf16 hb = (__bf16)v;
  float hf = (float)hb;
  __bf16 lb = (__bf16)(v - hf);
  h = bfbits(hb); l = bfbits(lb);
}

// ---------------- graph build ----------------

__global__ void hist_kernel(const int* __restrict__ src, const int* __restrict__ dst,
                            int* __restrict__ cnt_src, int* __restrict__ cnt_dst, int E) {
  int e = blockIdx.x * blockDim.x + threadIdx.x;
  if (e < E) {
    atomicAdd(&cnt_src[src[e]], 1);
    atomicAdd(&cnt_dst[dst[e]], 1);
  }
}

__global__ __launch_bounds__(1024) void scan_kernel(const int* __restrict__ in, int* __restrict__ out, int n) {
  __shared__ int tmp[4096];
  int tid = threadIdx.x;
  for (int i = tid; i < n; i += 1024) tmp[i] = in[i];
  __syncthreads();
  for (int off = 1; off < n; off <<= 1) {
    int v[4];
    int c = 0;
    for (int i = tid; i < n; i += 1024) { v[c++] = (i >= off) ? tmp[i - off] : 0; }
    __syncthreads();
    c = 0;
    for (int i = tid; i < n; i += 1024) { tmp[i] += v[c++]; }
    __syncthreads();
  }
  for (int i = tid; i < n; i += 1024) out[i + 1] = tmp[i];
  if (tid == 0) out[0] = 0;
}

__global__ void scatter_kernel(const int* __restrict__ src, const int* __restrict__ dst,
                               const int* __restrict__ csc_off, const int* __restrict__ csr_off,
                               int* __restrict__ fill_dst, int* __restrict__ fill_src,
                               int* __restrict__ csc_src, int* __restrict__ csr_dst, int E) {
  int e = blockIdx.x * blockDim.x + threadIdx.x;
  if (e < E) {
    int s = src[e], d = dst[e];
    int p = atomicAdd(&fill_dst[d], 1);
    csc_src[csc_off[d] + p] = s;
    int q = atomicAdd(&fill_src[s], 1);
    csr_dst[csr_off[s] + q] = d;
  }
}

__global__ void dis0_kernel(const int* __restrict__ cnt_dst, float* __restrict__ dis, int n) {
  int i = blockIdx.x * blockDim.x + threadIdx.x;
  if (i < n) dis[i] = rsqrtf((float)cnt_dst[i] + 1.0f);
}

__global__ void pnorm_kernel(const float* __restrict__ p, float* __restrict__ outv, int C) {
  int tid = threadIdx.x;
  float acc = 0.f;
  for (int j = tid; j < C; j += 256) { float v = p[j]; acc += v * v; }
  for (int o = 32; o > 0; o >>= 1) acc += __shfl_down(acc, o);
  __shared__ float red[4];
  if ((tid & 63) == 0) red[tid >> 6] = acc;
  __syncthreads();
  if (tid == 0) outv[0] = sqrtf(red[0] + red[1] + red[2] + red[3]);
}

// ---------------- scoring / topk ----------------

// fused: s[i] = tanh(x.p/||p||) and the sort key
__global__ void score_key(const float* __restrict__ X, const float* __restrict__ p,
                          const float* __restrict__ pn, float* __restrict__ s,
                          unsigned long long* __restrict__ keys, int C) {
  int i = blockIdx.x;
  int tid = threadIdx.x;
  float acc = 0.f;
  for (int j = tid; j < C; j += 256) acc += X[(size_t)i * C + j] * p[j];
  for (int o = 32; o > 0; o >>= 1) acc += __shfl_down(acc, o);
  __shared__ float red[4];
  if ((tid & 63) == 0) red[tid >> 6] = acc;
  __syncthreads();
  if (tid == 0) {
    float sv = tanhf((red[0] + red[1] + red[2] + red[3]) / pn[0]);
    s[i] = sv;
    unsigned u = __float_as_uint(sv);
    unsigned m = (u & 0x80000000u) ? ~u : (u | 0x80000000u);
    keys[i] = (((unsigned long long)(~m)) << 32) | (unsigned)i;  // desc value, asc index
  }
}

__global__ __launch_bounds__(256) void rank_count(const unsigned long long* __restrict__ keys,
                                                  int* __restrict__ rank) {
  __shared__ unsigned long long kk[512];
  int tid = threadIdx.x;
  int cand = blockIdx.x * 256 + tid;
  int base = blockIdx.y * 512;
  kk[tid] = keys[base + tid];
  kk[tid + 256] = keys[base + tid + 256];
  __syncthreads();
  unsigned long long kc = keys[cand];
  int c = 0;
#pragma unroll 8
  for (int t = 0; t < 512; ++t) c += (kk[t] < kc) ? 1 : 0;
  atomicAdd(&rank[cand], c);
}

__global__ void rank_place(const float* __restrict__ s, const int* __restrict__ rank, int k, int n,
                           int* __restrict__ kept, int* __restrict__ perm, float* __restrict__ vals) {
  int i = blockIdx.x * blockDim.x + threadIdx.x;
  if (i < n) {
    int r = rank[i];
    if (r < k) { perm[r] = i; vals[r] = s[i]; kept[i] = r; }
    else kept[i] = -1;
  }
}

// pooled row gather + gate + bf16 split, fused
__global__ void pool_split(const float* __restrict__ X, const int* __restrict__ perm,
                           const float* __restrict__ vals, unsigned short* __restrict__ h,
                           unsigned short* __restrict__ l, int C) {
  int a = blockIdx.x;
  int r = perm[a];
  float v = vals[a];
  for (int j = threadIdx.x; j < C; j += blockDim.x) {
    unsigned short hv, lv;
    split2(X[(size_t)r * C + j] * v, hv, lv);
    h[(size_t)a * C + j] = hv;
    l[(size_t)a * C + j] = lv;
  }
}

// ---------------- augment: row-parallel SpGEMM with LDS accumulator ----------------
// B1[ki,kj] = sum_k (M+I)[perm[ki],k] * (M+I)[k,perm[kj]], +I folded on diag.
__global__ __launch_bounds__(256) void aug_row(const int* __restrict__ csr_off,
                                               const int* __restrict__ csr_dst,
                                               const int* __restrict__ kept,
                                               const int* __restrict__ perm,
                                               float* __restrict__ B) {
  __shared__ float acc[NP1];
  int ki = blockIdx.x;
  int r = perm[ki];
  for (int t = threadIdx.x; t < NP1; t += 256) acc[t] = 0.f;
  __syncthreads();
  int s = csr_off[r], e = csr_off[r + 1];
  int nm = e - s;  // mids excluding the self loop
  int wave = threadIdx.x >> 6, lane = threadIdx.x & 63;
  for (int m = wave; m <= nm; m += 4) {
    int k = (m < nm) ? csr_dst[s + m] : r;  // m==nm: self loop of the first hop
    int s2 = csr_off[k], e2 = csr_off[k + 1];
    int n2 = e2 - s2;
    for (int t = lane; t <= n2; t += 64) {
      int j = (t < n2) ? csr_dst[s2 + t] : k;  // t==n2: self loop of the second hop
      int kj = kept[j];
      if (kj >= 0) atomicAdd(&acc[kj], 1.0f);
    }
  }
  __syncthreads();
  if (threadIdx.x == 0) acc[ki] += 1.0f;  // GCN's +I on the pooled graph
  __syncthreads();
  float* row = B + (size_t)ki * NP1;
  for (int t = threadIdx.x; t < NP1; t += 256) row[t] = acc[t];
}

__global__ void adddiag_kernel(float* __restrict__ B, int n) {
  int i = blockIdx.x * blockDim.x + threadIdx.x;
  if (i < n) B[(size_t)i * n + i] += 1.0f;
}

__global__ void colsum_part(const float* __restrict__ B, float* __restrict__ deg, int n) {
  int c = blockIdx.x * blockDim.x + threadIdx.x;
  int r0 = blockIdx.y * 16;
  float acc = 0.f;
#pragma unroll
  for (int r = 0; r < 16; ++r) acc += B[(size_t)(r0 + r) * n + c];
  atomicAdd(&deg[c], acc);
}

__global__ void dis_from_deg(const float* __restrict__ deg, float* __restrict__ dis, int n) {
  int i = blockIdx.x * blockDim.x + threadIdx.x;
  if (i < n) dis[i] = rsqrtf(deg[i]);
}

// ---------------- conversions ----------------

__global__ void split_rm(const float* __restrict__ in, unsigned short* __restrict__ h,
                         unsigned short* __restrict__ l, int n) {
  int i = blockIdx.x * blockDim.x + threadIdx.x;
  if (i < n) { unsigned short hv, lv; split2(in[i], hv, lv); h[i] = hv; l[i] = lv; }
}

// B1 fp32 -> bf16 row-major AND bf16 transposed (exact small ints), single pass
__global__ __launch_bounds__(256) void b1_dual(const float* __restrict__ in,
                                               unsigned short* __restrict__ rm,
                                               unsigned short* __restrict__ tr, int n) {
  __shared__ float t[64][65];
  int r0 = blockIdx.y * 64, c0 = blockIdx.x * 64;
  int tid = threadIdx.x;
#pragma unroll
  for (int q = 0; q < 16; ++q) {
    int idx = q * 256 + tid;
    int rr = idx >> 6, cc = idx & 63;
    float v = in[(size_t)(r0 + rr) * n + c0 + cc];
    t[rr][cc] = v;
    rm[(size_t)(r0 + rr) * n + c0 + cc] = bfbits((__bf16)v);
  }
  __syncthreads();
#pragma unroll
  for (int q = 0; q < 16; ++q) {
    int idx = q * 256 + tid;
    int cc = idx >> 6, rr = idx & 63;
    tr[(size_t)(c0 + cc) * n + r0 + rr] = bfbits((__bf16)t[rr][cc]);
  }
}

// fp32 [R][C] -> bf16 hi/lo transposed [C][R]; ol may be null
__global__ __launch_bounds__(256) void tsplit(const float* __restrict__ in, unsigned short* __restrict__ oh,
                                              unsigned short* __restrict__ ol, int R, int C) {
  __shared__ float t[64][65];
  int r0 = blockIdx.y * 64, c0 = blockIdx.x * 64;
  int tid = threadIdx.x;
#pragma unroll
  for (int q = 0; q < 16; ++q) {
    int idx = q * 256 + tid;
    int rr = idx >> 6, cc = idx & 63;
    t[rr][cc] = in[(size_t)(r0 + rr) * C + c0 + cc];
  }
  __syncthreads();
#pragma unroll
  for (int q = 0; q < 16; ++q) {
    int idx = q * 256 + tid;
    int cc = idx >> 6, rr = idx & 63;
    float v = t[rr][cc];
    __bf16 hb = (__bf16)v;
    size_t o = (size_t)(c0 + cc) * R + r0 + rr;
    oh[o] = bfbits(hb);
    if (ol) ol[o] = bfbits((__bf16)(v - (float)hb));
  }
}

// ---------------- misc elementwise ----------------

// up-path input: res + scatter(up), emitted directly as bf16 hi/lo split
__global__ void unpool_split(const float* __restrict__ res, const float* __restrict__ up,
                             const int* __restrict__ kept, unsigned short* __restrict__ h,
                             unsigned short* __restrict__ l, int n, int C) {
  int idx = blockIdx.x * blockDim.x + threadIdx.x;
  if (idx < n * C) {
    int r = idx / C;
    int j = idx - r * C;
    int k = kept[r];
    float v = res[idx];
    if (k >= 0) v += up[(size_t)k * C + j];
    unsigned short hv, lv;
    split2(v, hv, lv);
    h[idx] = hv; l[idx] = lv;
  }
}

// wave-per-row vectorized SpMM gather
template <int C>
__global__ __launch_bounds__(256) void spmm_gather_v(const float* __restrict__ Y,
                                                     const int* __restrict__ off,
                                                     const int* __restrict__ srcs,
                                                     const float* __restrict__ dis,
                                                     const float* __restrict__ bias,
                                                     float* __restrict__ out) {
  constexpr int VEC = C / 64;
  int w = threadIdx.x >> 6, lane = threadIdx.x & 63;
  int c = blockIdx.x * 4 + w;
  int j = lane * VEC;
  float acc[VEC];
  const float* p = Y + (size_t)c * C + j;
#pragma unroll
  for (int u = 0; u < VEC; ++u) acc[u] = p[u];
  int s = off[c], e = off[c + 1];
  for (int t = s; t < e; ++t) {
    const float* q = Y + (size_t)srcs[t] * C + j;
#pragma unroll
    for (int u = 0; u < VEC; ++u) acc[u] += q[u];
  }
  float d = dis[c];
  float* o = out + (size_t)c * C + j;
#pragma unroll
  for (int u = 0; u < VEC; ++u) o[u] = fmaxf(d * acc[u] + bias[j + u], 0.0f);
}

// ---------------- bf16-split MFMA GEMM (triple-buffered k-pipeline) ----------------
// C[i][j] = sum_k A[i][k] * B^T[j][k]; wave = 32x32, block = 4 waves = 64x64 tile.
// EPI: 0 plain fp32; 1 rowscale fp32; 2 rowscale + transposed split bf16 out; 3 rowscale+bias+relu fp32
template <int EPI, int AL, int BL, int K>
__global__ __launch_bounds__(256) void gemm16(
    const unsigned short* __restrict__ Ah, const unsigned short* __restrict__ Al,
    const unsigned short* __restrict__ Bh, const unsigned short* __restrict__ Bl,
    const int* __restrict__ permA, const int* __restrict__ permB,
    int M, int N,
    const float* __restrict__ rs, const float* __restrict__ bias,
    float* __restrict__ C, unsigned short* __restrict__ Th, unsigned short* __restrict__ Tl) {
  static_assert(K % 32 == 0, "K");
  const int wid = threadIdx.x >> 6, lane = threadIdx.x & 63;
  const int i0 = blockIdx.y * 64 + (wid >> 1) * 32;
  const int j0 = blockIdx.x * 64 + (wid & 1) * 32;
  const int lr = lane & 15, lk = lane >> 4;
  size_t aoff[2], boff[2];
#pragma unroll
  for (int t = 0; t < 2; ++t) {
    int ia = i0 + 16 * t + lr;
    int ra = permA ? permA[ia] : ia;
    aoff[t] = (size_t)ra * K + lk * 8;
    int jb = j0 + 16 * t + lr;
    int rb = permB ? permB[jb] : jb;
    boff[t] = (size_t)rb * K + lk * 8;
  }
  const f32x4 z = {0.f, 0.f, 0.f, 0.f};
  f32x4 acc[2][2];
  acc[0][0] = z; acc[0][1] = z; acc[1][0] = z; acc[1][1] = z;

  bf16x8 ahf[3][2], bhf[3][2], alf[3][2], blf[3][2];
  auto loadk = [&](int k0, int b) {
    ahf[b][0] = *(const bf16x8*)(Ah + aoff[0] + k0);
    ahf[b][1] = *(const bf16x8*)(Ah + aoff[1] + k0);
    bhf[b][0] = *(const bf16x8*)(Bh + boff[0] + k0);
    bhf[b][1] = *(const bf16x8*)(Bh + boff[1] + k0);
    if constexpr (AL) {
      alf[b][0] = *(const bf16x8*)(Al + aoff[0] + k0);
      alf[b][1] = *(const bf16x8*)(Al + aoff[1] + k0);
    }
    if constexpr (BL) {
      blf[b][0] = *(const bf16x8*)(Bl + boff[0] + k0);
      blf[b][1] = *(const bf16x8*)(Bl + boff[1] + k0);
    }
  };
  auto domm = [&](int b) {
#pragma unroll
    for (int am = 0; am < 2; ++am)
#pragma unroll
      for (int bn = 0; bn < 2; ++bn) {
        acc[am][bn] = __builtin_amdgcn_mfma_f32_16x16x32_bf16(ahf[b][am], bhf[b][bn], acc[am][bn], 0, 0, 0);
        if constexpr (BL)
          acc[am][bn] = __builtin_amdgcn_mfma_f32_16x16x32_bf16(ahf[b][am], blf[b][bn], acc[am][bn], 0, 0, 0);
        if constexpr (AL)
          acc[am][bn] = __builtin_amdgcn_mfma_f32_16x16x32_bf16(alf[b][am], bhf[b][bn], acc[am][bn], 0, 0, 0);
      }
  };

  loadk(0, 0);
  if constexpr (K > 32) loadk(32, 1);
#pragma unroll
  for (int k0 = 0; k0 < K; k0 += 32) {
    const int cur = (k0 >> 5) % 3;
    if (k0 + 64 < K) loadk(k0 + 64, (cur + 2) % 3);
    domm(cur);
  }

#pragma unroll
  for (int am = 0; am < 2; ++am)
#pragma unroll
    for (int bn = 0; bn < 2; ++bn) {
      int ib = i0 + 16 * am + lk * 4;
      int j = j0 + 16 * bn + lr;
      f32x4 a = acc[am][bn];
      if constexpr (EPI == 0) {
#pragma unroll
        for (int r = 0; r < 4; ++r) C[(size_t)(ib + r) * N + j] = a[r];
      } else if constexpr (EPI == 1) {
#pragma unroll
        for (int r = 0; r < 4; ++r) C[(size_t)(ib + r) * N + j] = rs[ib + r] * a[r];
      } else if constexpr (EPI == 2) {
        unsigned long long hp = 0, lp = 0;
#pragma unroll
        for (int r = 0; r < 4; ++r) {
          unsigned short hv, lv;
          split2(rs[ib + r] * a[r], hv, lv);
          hp |= ((unsigned long long)hv) << (16 * r);
          lp |= ((unsigned long long)lv) << (16 * r);
        }
        *(unsigned long long*)&Th[(size_t)j * M + ib] = hp;
        *(unsigned long long*)&Tl[(size_t)j * M + ib] = lp;
      } else {
#pragma unroll
        for (int r = 0; r < 4; ++r)
          C[(size_t)(ib + r) * N + j] = fmaxf(rs[ib + r] * a[r] + bias[j], 0.0f);
      }
    }
}

// ---------------- launch ----------------

extern "C" void kernel_launch(void* const* d_in, const int* in_sizes, int n_in,
                              void* d_out, int out_size, void* d_ws, size_t ws_size,
                              hipStream_t stream) {
  (void)in_sizes; (void)n_in; (void)out_size; (void)ws_size;
  const float* x  = (const float*)d_in[0];
  const int* ei   = (const int*)d_in[1];
  const int* esrc = ei;
  const int* edst = ei + EE;
  const float* w0 = (const float*)d_in[2];
  const float* b0 = (const float*)d_in[3];
  const float* w1 = (const float*)d_in[4];
  const float* b1 = (const float*)d_in[5];
  const float* w2 = (const float*)d_in[6];
  const float* b2 = (const float*)d_in[7];
  const float* w3 = (const float*)d_in[8];
  const float* b3 = (const float*)d_in[9];
  const float* w4 = (const float*)d_in[10];
  const float* b4 = (const float*)d_in[11];
  const float* p0 = (const float*)d_in[12];
  const float* p1 = (const float*)d_in[13];
  float* out = (float*)d_out;

  char* ws = (char*)d_ws;
  size_t off = 0;
  auto alloc = [&](size_t b) { void* p = ws + off; off += (b + 255) & ~(size_t)255; return p; };

  int* csc_off = (int*)alloc(4 * (NN + 1));
  int* csr_off = (int*)alloc(4 * (NN + 1));
  int* csc_src = (int*)alloc(4 * EE);
  int* csr_dst = (int*)alloc(4 * EE);

  // zeroed region: counts + degs + ranks
  size_t zero_bytes = 4 * NN * 4 + 4 * NP1 + 4 * NP2 + 4 * NN + 4 * NP1;
  int* cnts    = (int*)alloc(zero_bytes);
  int* cnt_dst = cnts;
  int* cnt_src = cnts + NN;
  int* fill_dst = cnts + 2 * NN;
  int* fill_src = cnts + 3 * NN;
  float* deg1 = (float*)(cnts + 4 * NN);
  float* deg2 = deg1 + NP1;
  int* rank0 = (int*)(deg2 + NP2);
  int* rank1 = rank0 + NN;

  int* kept0 = (int*)alloc(4 * NN);
  int* perm0 = (int*)alloc(4 * NP1);
  int* kept1 = (int*)alloc(4 * NP1);
  int* perm1 = (int*)alloc(4 * NP2);
  float* dis0 = (float*)alloc(4 * NN);
  float* dis1 = (float*)alloc(4 * NP1);
  float* dis2 = (float*)alloc(4 * NP2);
  float* pnrm = (float*)alloc(8);
  float* s0   = (float*)alloc(4 * NN);
  float* vals0 = (float*)alloc(4 * NP1);
  float* s1   = (float*)alloc(4 * NP1);
  float* vals1 = (float*)alloc(4 * NP2);
  unsigned long long* keys0 = (unsigned long long*)alloc(8 * NN);
  unsigned long long* keys1 = (unsigned long long*)alloc(8 * NP1);

  const size_t MB = 1024 * 1024;
  // B1 region (16MB): after B1 fp32 dies, hosts B2 / B2t splits
  char* regB1 = (char*)alloc(16 * MB);
  float* B1   = (float*)regB1;                       // 2048^2 fp32
  float* B2   = (float*)regB1;                       // 1024^2 fp32 (4MB)  [after B1 dead]
  unsigned short* B2th = (unsigned short*)(regB1 + 4 * MB);   // 2MB
  unsigned short* B2tl = (unsigned short*)(regB1 + 6 * MB);   // 2MB

  unsigned short* B1rm = (unsigned short*)alloc(8 * MB);  // 2048^2 bf16 row-major (exact)
  unsigned short* B1t  = (unsigned short*)alloc(8 * MB);  // 2048^2 bf16 transposed (exact)
  float* res0 = (float*)alloc(4 * MB);   // 4096x256
  float* res1 = (float*)alloc(4 * MB);   // 2048x512
  float* yreg = (float*)alloc(4 * MB);   // y0 (4096x256) then y4 (4096x128)
  float* outreg = (float*)alloc(2 * MB); // out2 (1024x512) then out3 (2048x256)
  float* out2 = outreg, *out3 = outreg;
  char* ytreg = (char*)alloc(4 * MB);    // Y1t h+l -> Y2t h+l -> Y3t h+l
  unsigned short* Y1th = (unsigned short*)ytreg;
  unsigned short* Y1tl = (unsigned short*)(ytreg + 2 * MB);
  unsigned short* Y2th = (unsigned short*)ytreg;
  unsigned short* Y2tl = (unsigned short*)(ytreg + 1 * MB);
  unsigned short* Y3th = (unsigned short*)ytreg;
  unsigned short* Y3tl = (unsigned short*)(ytreg + 1 * MB);
  char* xsreg = (char*)alloc(4 * MB);    // x3 h+l (2+2MB) -> x4 h+l (2+2MB)
  unsigned short* x3h = (unsigned short*)xsreg;
  unsigned short* x3l = (unsigned short*)(xsreg + 2 * MB);
  unsigned short* x4h = (unsigned short*)xsreg;
  unsigned short* x4l = (unsigned short*)(xsreg + 2 * MB);
  unsigned short* xh = (unsigned short*)alloc(1 * MB);   // 4096x128
  unsigned short* xl = (unsigned short*)alloc(1 * MB);
  char* xsm = (char*)alloc(2 * MB);      // x1 h+l (1+1MB) -> x2 h+l (1+1MB)
  unsigned short* x1h = (unsigned short*)xsm;
  unsigned short* x1l = (unsigned short*)(xsm + 1 * MB);
  unsigned short* x2h = (unsigned short*)xsm;
  unsigned short* x2l = (unsigned short*)(xsm + 1 * MB);
  // weights (transposed splits)
  unsigned short* Wt0h = (unsigned short*)alloc(256 * 128 * 2);
  unsigned short* Wt0l = (unsigned short*)alloc(256 * 128 * 2);
  unsigned short* Wt1h = (unsigned short*)alloc(512 * 256 * 2);
  unsigned short* Wt1l = (unsigned short*)alloc(512 * 256 * 2);
  unsigned short* Wt2h = (unsigned short*)alloc(512 * 512 * 2);
  unsigned short* Wt2l = (unsigned short*)alloc(512 * 512 * 2);
  unsigned short* Wt3h = (unsigned short*)alloc(256 * 512 * 2);
  unsigned short* Wt3l = (unsigned short*)alloc(256 * 512 * 2);
  unsigned short* Wt4h = (unsigned short*)alloc(128 * 256 * 2);
  unsigned short* Wt4l = (unsigned short*)alloc(128 * 256 * 2);

  hipMemsetAsync(cnts, 0, zero_bytes, stream);

  // graph build
  hist_kernel<<<EE / 256, 256, 0, stream>>>(esrc, edst, cnt_src, cnt_dst, EE);
  scan_kernel<<<1, 1024, 0, stream>>>(cnt_dst, csc_off, NN);
  scan_kernel<<<1, 1024, 0, stream>>>(cnt_src, csr_off, NN);
  scatter_kernel<<<EE / 256, 256, 0, stream>>>(esrc, edst, csc_off, csr_off,
                                               fill_dst, fill_src, csc_src, csr_dst, EE);
  dis0_kernel<<<NN / 256, 256, 0, stream>>>(cnt_dst, dis0, NN);
  pnorm_kernel<<<1, 256, 0, stream>>>(p0, pnrm + 0, 256);
  pnorm_kernel<<<1, 256, 0, stream>>>(p1, pnrm + 1, 512);

  // weight conversions
  tsplit<<<dim3(4, 2), 256, 0, stream>>>(w0, Wt0h, Wt0l, 128, 256);
  tsplit<<<dim3(8, 4), 256, 0, stream>>>(w1, Wt1h, Wt1l, 256, 512);
  tsplit<<<dim3(8, 8), 256, 0, stream>>>(w2, Wt2h, Wt2l, 512, 512);
  tsplit<<<dim3(4, 8), 256, 0, stream>>>(w3, Wt3h, Wt3l, 512, 256);
  tsplit<<<dim3(2, 4), 256, 0, stream>>>(w4, Wt4h, Wt4l, 256, 128);
  split_rm<<<(NN * 128) / 256, 256, 0, stream>>>(x, xh, xl, NN * 128);

  // gcn0
  gemm16<1, 1, 1, 128><<<dim3(4, 64), 256, 0, stream>>>(xh, xl, Wt0h, Wt0l, nullptr, nullptr,
                                                        NN, 256, dis0, nullptr, yreg, nullptr, nullptr);
  spmm_gather_v<256><<<NN / 4, 256, 0, stream>>>(yreg, csc_off, csc_src, dis0, b0, res0);

  // pool0
  score_key<<<NN, 256, 0, stream>>>(res0, p0, pnrm + 0, s0, keys0, 256);
  rank_count<<<dim3(NN / 256, NN / 512), 256, 0, stream>>>(keys0, rank0);
  rank_place<<<NN / 256, 256, 0, stream>>>(s0, rank0, NP1, NN, kept0, perm0, vals0);
  pool_split<<<NP1, 256, 0, stream>>>(res0, perm0, vals0, x1h, x1l, 256);

  // augment0 -> B1 (+I folded), deg, dis; bf16 copies
  aug_row<<<NP1, 256, 0, stream>>>(csr_off, csr_dst, kept0, perm0, B1);
  colsum_part<<<dim3(NP1 / 256, NP1 / 16), 256, 0, stream>>>(B1, deg1, NP1);
  dis_from_deg<<<NP1 / 256, 256, 0, stream>>>(deg1, dis1, NP1);
  b1_dual<<<dim3(32, 32), 256, 0, stream>>>(B1, B1rm, B1t, NP1);
  // B1 fp32 dead after b1_dual.

  // gcn1
  gemm16<2, 1, 1, 256><<<dim3(8, 32), 256, 0, stream>>>(x1h, x1l, Wt1h, Wt1l, nullptr, nullptr,
                                                        NP1, 512, dis1, nullptr, nullptr, Y1th, Y1tl);
  gemm16<3, 0, 1, 2048><<<dim3(8, 32), 256, 0, stream>>>(B1t, nullptr, Y1th, Y1tl, nullptr, nullptr,
                                                         NP1, 512, dis1, b1, res1, nullptr, nullptr);

  // pool1
  score_key<<<NP1, 256, 0, stream>>>(res1, p1, pnrm + 1, s1, keys1, 512);
  rank_count<<<dim3(NP1 / 256, NP1 / 512), 256, 0, stream>>>(keys1, rank1);
  rank_place<<<NP1 / 256, 256, 0, stream>>>(s1, rank1, NP2, NP1, kept1, perm1, vals1);
  pool_split<<<NP2, 256, 0, stream>>>(res1, perm1, vals1, x2h, x2l, 512);

  // augment1 (dense, exact bf16): B2 = B1[perm1,:] @ B1[:,perm1]
  gemm16<0, 0, 0, 2048><<<dim3(16, 16), 256, 0, stream>>>(B1rm, nullptr, B1t, nullptr, perm1, perm1,
                                                          NP2, NP2, nullptr, nullptr, B2, nullptr, nullptr);
  adddiag_kernel<<<NP2 / 256, 256, 0, stream>>>(B2, NP2);
  colsum_part<<<dim3(NP2 / 256, NP2 / 16), 256, 0, stream>>>(B2, deg2, NP2);
  dis_from_deg<<<NP2 / 256, 256, 0, stream>>>(deg2, dis2, NP2);
  tsplit<<<dim3(16, 16), 256, 0, stream>>>(B2, B2th, B2tl, NP2, NP2);

  // gcn2 (bottleneck)
  gemm16<2, 1, 1, 512><<<dim3(8, 16), 256, 0, stream>>>(x2h, x2l, Wt2h, Wt2l, nullptr, nullptr,
                                                        NP2, 512, dis2, nullptr, nullptr, Y2th, Y2tl);
  gemm16<3, 1, 1, 1024><<<dim3(8, 16), 256, 0, stream>>>(B2th, B2tl, Y2th, Y2tl, nullptr, nullptr,
                                                         NP2, 512, dis2, b2, out2, nullptr, nullptr);

  // up1
  unpool_split<<<(NP1 * 512) / 256, 256, 0, stream>>>(res1, out2, kept1, x3h, x3l, NP1, 512);
  gemm16<2, 1, 1, 512><<<dim3(4, 32), 256, 0, stream>>>(x3h, x3l, Wt3h, Wt3l, nullptr, nullptr,
                                                        NP1, 256, dis1, nullptr, nullptr, Y3th, Y3tl);
  gemm16<3, 0, 1, 2048><<<dim3(4, 32), 256, 0, stream>>>(B1t, nullptr, Y3th, Y3tl, nullptr, nullptr,
                                                         NP1, 256, dis1, b3, out3, nullptr, nullptr);

  // up0
  unpool_split<<<(NN * 256) / 256, 256, 0, stream>>>(res0, out3, kept0, x4h, x4l, NN, 256);
  gemm16<1, 1, 1, 256><<<dim3(2, 64), 256, 0, stream>>>(x4h, x4l, Wt4h, Wt4l, nullptr, nullptr,
                                                        NN, 128, dis0, nullptr, yreg, nullptr, nullptr);
  spmm_gather_v<128><<<NN / 4, 256, 0, stream>>>(yreg, csc_off, csc_src, dis0, b4, out);
}

// Round 5
// 430.967 us; speedup vs baseline: 2.4985x; 1.0361x over previous
//
#include <hip/hip_runtime.h>

#define NN 4096
#define EE 131072
#define NP1 2048
#define NP2 1024

typedef __attribute__((ext_vector_type(8))) __bf16 bf16x8;
typedef __attribute__((ext_vector_type(4))) float f32x4;

static __device__ inline unsigned short bfbits(__bf16 b) {
  union { __bf16 x; unsigned short u; } c; c.x = b; return c.u;
}
static __device__ inline void split2(float v, unsigned short& h, unsigned short& l) {
  __bf16 hb = (__bf16)v;
  float hf = (float)hb;
  __bf16 lb = (__bf16)(v - hf);
  h = bfbits(hb); l = bfbits(lb);
}

// ---------------- graph build ----------------

__global__ void hist_kernel(const int* __restrict__ src, const int* __restrict__ dst,
                            int* __restrict__ cnt_src, int* __restrict__ cnt_dst, int E) {
  int e = blockIdx.x * blockDim.x + threadIdx.x;
  if (e < E) {
    atomicAdd(&cnt_src[src[e]], 1);
    atomicAdd(&cnt_dst[dst[e]], 1);
  }
}

__global__ __launch_bounds__(1024) void scan_kernel(const int* __restrict__ in, int* __restrict__ out, int n) {
  __shared__ int tmp[4096];
  int tid = threadIdx.x;
  for (int i = tid; i < n; i += 1024) tmp[i] = in[i];
  __syncthreads();
  for (int off = 1; off < n; off <<= 1) {
    int v[4];
    int c = 0;
    for (int i = tid; i < n; i += 1024) { v[c++] = (i >= off) ? tmp[i - off] : 0; }
    __syncthreads();
    c = 0;
    for (int i = tid; i < n; i += 1024) { tmp[i] += v[c++]; }
    __syncthreads();
  }
  for (int i = tid; i < n; i += 1024) out[i + 1] = tmp[i];
  if (tid == 0) out[0] = 0;
}

__global__ void scatter_kernel(const int* __restrict__ src, const int* __restrict__ dst,
                               const int* __restrict__ csc_off, const int* __restrict__ csr_off,
                               int* __restrict__ fill_dst, int* __restrict__ fill_src,
                               int* __restrict__ csc_src, int* __restrict__ csr_dst, int E) {
  int e = blockIdx.x * blockDim.x + threadIdx.x;
  if (e < E) {
    int s = src[e], d = dst[e];
    int p = atomicAdd(&fill_dst[d], 1);
    csc_src[csc_off[d] + p] = s;
    int q = atomicAdd(&fill_src[s], 1);
    csr_dst[csr_off[s] + q] = d;
  }
}

__global__ void dis0_kernel(const int* __restrict__ cnt_dst, float* __restrict__ dis, int n) {
  int i = blockIdx.x * blockDim.x + threadIdx.x;
  if (i < n) dis[i] = rsqrtf((float)cnt_dst[i] + 1.0f);
}

__global__ void pnorm_kernel(const float* __restrict__ p, float* __restrict__ outv, int C) {
  int tid = threadIdx.x;
  float acc = 0.f;
  for (int j = tid; j < C; j += 256) { float v = p[j]; acc += v * v; }
  for (int o = 32; o > 0; o >>= 1) acc += __shfl_down(acc, o);
  __shared__ float red[4];
  if ((tid & 63) == 0) red[tid >> 6] = acc;
  __syncthreads();
  if (tid == 0) outv[0] = sqrtf(red[0] + red[1] + red[2] + red[3]);
}

// ---------------- scoring / topk ----------------

__global__ void score_key(const float* __restrict__ X, const float* __restrict__ p,
                          const float* __restrict__ pn, float* __restrict__ s,
                          unsigned long long* __restrict__ keys, int C) {
  int i = blockIdx.x;
  int tid = threadIdx.x;
  float acc = 0.f;
  for (int j = tid; j < C; j += 256) acc += X[(size_t)i * C + j] * p[j];
  for (int o = 32; o > 0; o >>= 1) acc += __shfl_down(acc, o);
  __shared__ float red[4];
  if ((tid & 63) == 0) red[tid >> 6] = acc;
  __syncthreads();
  if (tid == 0) {
    float sv = tanhf((red[0] + red[1] + red[2] + red[3]) / pn[0]);
    s[i] = sv;
    unsigned u = __float_as_uint(sv);
    unsigned m = (u & 0x80000000u) ? ~u : (u | 0x80000000u);
    keys[i] = (((unsigned long long)(~m)) << 32) | (unsigned)i;  // desc value, asc index
  }
}

__global__ __launch_bounds__(256) void rank_count(const unsigned long long* __restrict__ keys,
                                                  int* __restrict__ rank) {
  __shared__ unsigned long long kk[512];
  int tid = threadIdx.x;
  int cand = blockIdx.x * 256 + tid;
  int base = blockIdx.y * 512;
  kk[tid] = keys[base + tid];
  kk[tid + 256] = keys[base + tid + 256];
  __syncthreads();
  unsigned long long kc = keys[cand];
  int c = 0;
#pragma unroll 8
  for (int t = 0; t < 512; ++t) c += (kk[t] < kc) ? 1 : 0;
  atomicAdd(&rank[cand], c);
}

__global__ void rank_place(const float* __restrict__ s, const int* __restrict__ rank, int k, int n,
                           int* __restrict__ kept, int* __restrict__ perm, float* __restrict__ vals) {
  int i = blockIdx.x * blockDim.x + threadIdx.x;
  if (i < n) {
    int r = rank[i];
    if (r < k) { perm[r] = i; vals[r] = s[i]; kept[i] = r; }
    else kept[i] = -1;
  }
}

__global__ void pool_split(const float* __restrict__ X, const int* __restrict__ perm,
                           const float* __restrict__ vals, unsigned short* __restrict__ h,
                           unsigned short* __restrict__ l, int C) {
  int a = blockIdx.x;
  int r = perm[a];
  float v = vals[a];
  for (int j = threadIdx.x; j < C; j += blockDim.x) {
    unsigned short hv, lv;
    split2(X[(size_t)r * C + j] * v, hv, lv);
    h[(size_t)a * C + j] = hv;
    l[(size_t)a * C + j] = lv;
  }
}

// ---------------- augment: row-parallel SpGEMM with LDS accumulator ----------------

__global__ __launch_bounds__(256) void aug_row(const int* __restrict__ csr_off,
                                               const int* __restrict__ csr_dst,
                                               const int* __restrict__ kept,
                                               const int* __restrict__ perm,
                                               float* __restrict__ B) {
  __shared__ float acc[NP1];
  int ki = blockIdx.x;
  int r = perm[ki];
  for (int t = threadIdx.x; t < NP1; t += 256) acc[t] = 0.f;
  __syncthreads();
  int s = csr_off[r], e = csr_off[r + 1];
  int nm = e - s;
  int wave = threadIdx.x >> 6, lane = threadIdx.x & 63;
  for (int m = wave; m <= nm; m += 4) {
    int k = (m < nm) ? csr_dst[s + m] : r;
    int s2 = csr_off[k], e2 = csr_off[k + 1];
    int n2 = e2 - s2;
    for (int t = lane; t <= n2; t += 64) {
      int j = (t < n2) ? csr_dst[s2 + t] : k;
      int kj = kept[j];
      if (kj >= 0) atomicAdd(&acc[kj], 1.0f);
    }
  }
  __syncthreads();
  if (threadIdx.x == 0) acc[ki] += 1.0f;
  __syncthreads();
  float* row = B + (size_t)ki * NP1;
  for (int t = threadIdx.x; t < NP1; t += 256) row[t] = acc[t];
}

__global__ void colsum_part(const float* __restrict__ B, float* __restrict__ deg, int n) {
  int c = blockIdx.x * blockDim.x + threadIdx.x;
  int r0 = blockIdx.y * 16;
  float acc = 0.f;
#pragma unroll
  for (int r = 0; r < 16; ++r) acc += B[(size_t)(r0 + r) * n + c];
  atomicAdd(&deg[c], acc);
}

__global__ void dis_from_deg(const float* __restrict__ deg, float* __restrict__ dis, int n) {
  int i = blockIdx.x * blockDim.x + threadIdx.x;
  if (i < n) dis[i] = rsqrtf(deg[i]);
}

// ---------------- conversions ----------------

__global__ void split_rm(const float* __restrict__ in, unsigned short* __restrict__ h,
                         unsigned short* __restrict__ l, int n) {
  int i = blockIdx.x * blockDim.x + threadIdx.x;
  if (i < n) { unsigned short hv, lv; split2(in[i], hv, lv); h[i] = hv; l[i] = lv; }
}

__global__ __launch_bounds__(256) void b1_dual(const float* __restrict__ in,
                                               unsigned short* __restrict__ rm,
                                               unsigned short* __restrict__ tr, int n) {
  __shared__ float t[64][65];
  int r0 = blockIdx.y * 64, c0 = blockIdx.x * 64;
  int tid = threadIdx.x;
#pragma unroll
  for (int q = 0; q < 16; ++q) {
    int idx = q * 256 + tid;
    int rr = idx >> 6, cc = idx & 63;
    float v = in[(size_t)(r0 + rr) * n + c0 + cc];
    t[rr][cc] = v;
    rm[(size_t)(r0 + rr) * n + c0 + cc] = bfbits((__bf16)v);
  }
  __syncthreads();
#pragma unroll
  for (int q = 0; q < 16; ++q) {
    int idx = q * 256 + tid;
    int cc = idx >> 6, rr = idx & 63;
    tr[(size_t)(c0 + cc) * n + r0 + rr] = bfbits((__bf16)t[rr][cc]);
  }
}

__global__ __launch_bounds__(256) void tsplit(const float* __restrict__ in, unsigned short* __restrict__ oh,
                                              unsigned short* __restrict__ ol, int R, int C) {
  __shared__ float t[64][65];
  int r0 = blockIdx.y * 64, c0 = blockIdx.x * 64;
  int tid = threadIdx.x;
#pragma unroll
  for (int q = 0; q < 16; ++q) {
    int idx = q * 256 + tid;
    int rr = idx >> 6, cc = idx & 63;
    t[rr][cc] = in[(size_t)(r0 + rr) * C + c0 + cc];
  }
  __syncthreads();
#pragma unroll
  for (int q = 0; q < 16; ++q) {
    int idx = q * 256 + tid;
    int cc = idx >> 6, rr = idx & 63;
    float v = t[rr][cc];
    __bf16 hb = (__bf16)v;
    size_t o = (size_t)(c0 + cc) * R + r0 + rr;
    oh[o] = bfbits(hb);
    if (ol) ol[o] = bfbits((__bf16)(v - (float)hb));
  }
}

// ---------------- misc elementwise ----------------

__global__ void unpool_split(const float* __restrict__ res, const float* __restrict__ up,
                             const int* __restrict__ kept, unsigned short* __restrict__ h,
                             unsigned short* __restrict__ l, int n, int C) {
  int idx = blockIdx.x * blockDim.x + threadIdx.x;
  if (idx < n * C) {
    int r = idx / C;
    int j = idx - r * C;
    int k = kept[r];
    float v = res[idx];
    if (k >= 0) v += up[(size_t)k * C + j];
    unsigned short hv, lv;
    split2(v, hv, lv);
    h[idx] = hv; l[idx] = lv;
  }
}

template <int C>
__global__ __launch_bounds__(256) void spmm_gather_v(const float* __restrict__ Y,
                                                     const int* __restrict__ off,
                                                     const int* __restrict__ srcs,
                                                     const float* __restrict__ dis,
                                                     const float* __restrict__ bias,
                                                     float* __restrict__ out) {
  constexpr int VEC = C / 64;
  int w = threadIdx.x >> 6, lane = threadIdx.x & 63;
  int c = blockIdx.x * 4 + w;
  int j = lane * VEC;
  float acc[VEC];
  const float* p = Y + (size_t)c * C + j;
#pragma unroll
  for (int u = 0; u < VEC; ++u) acc[u] = p[u];
  int s = off[c], e = off[c + 1];
  for (int t = s; t < e; ++t) {
    const float* q = Y + (size_t)srcs[t] * C + j;
#pragma unroll
    for (int u = 0; u < VEC; ++u) acc[u] += q[u];
  }
  float d = dis[c];
  float* o = out + (size_t)c * C + j;
#pragma unroll
  for (int u = 0; u < VEC; ++u) o[u] = fmaxf(d * acc[u] + bias[j + u], 0.0f);
}

// ---------------- split-K combine epilogues ----------------

// out[i][j] = relu(rs[i]*(p0+p1)[i][j] + bias[j]); partials p[z*M*N + ...]
__global__ void ep3(const float* __restrict__ p, const float* __restrict__ rs,
                    const float* __restrict__ bias, float* __restrict__ outp, int M, int N) {
  int idx = blockIdx.x * blockDim.x + threadIdx.x;
  int j4 = (idx * 4) % N, i = (idx * 4) / N;
  float4 a = *(const float4*)(p + (size_t)i * N + j4);
  float4 b = *(const float4*)(p + (size_t)(M + i) * N + j4);
  float r = rs[i];
  float4 o;
  o.x = fmaxf(r * (a.x + b.x) + bias[j4 + 0], 0.f);
  o.y = fmaxf(r * (a.y + b.y) + bias[j4 + 1], 0.f);
  o.z = fmaxf(r * (a.z + b.z) + bias[j4 + 2], 0.f);
  o.w = fmaxf(r * (a.w + b.w) + bias[j4 + 3], 0.f);
  *(float4*)(outp + (size_t)i * N + j4) = o;
}

// B[i][j] = (p0+p1)[i][j] + (i==j)
__global__ void ep_aug(const float* __restrict__ p, float* __restrict__ B, int n) {
  int idx = blockIdx.x * blockDim.x + threadIdx.x;
  int j4 = (idx * 4) % n, i = (idx * 4) / n;
  float4 a = *(const float4*)(p + (size_t)i * n + j4);
  float4 b = *(const float4*)(p + (size_t)(n + i) * n + j4);
  float4 o = {a.x + b.x, a.y + b.y, a.z + b.z, a.w + b.w};
  if (i >= j4 && i < j4 + 4) (&o.x)[i - j4] += 1.0f;
  *(float4*)(B + (size_t)i * n + j4) = o;
}

// ---------------- bf16-split MFMA GEMM (4-deep pipeline, split-K, XCD swizzle) ----------------
// C[i][j] = sum_k A[i][k] * B^T[j][k]; wave = 32x32, block = 4 waves = 64x64 tile.
// Row stride of A/B is S*KK; split z covers k in [z*KK, (z+1)*KK).
// S>1: plain partial write to C + z*M*N. S==1 EPI: 0 plain; 1 rowscale; 2 rowscale+split-T; 3 rowscale+bias+relu
template <int EPI, int AL, int BL, int KK, int S>
__global__ __launch_bounds__(256) void gemm16(
    const unsigned short* __restrict__ Ah, const unsigned short* __restrict__ Al,
    const unsigned short* __restrict__ Bh, const unsigned short* __restrict__ Bl,
    const int* __restrict__ permA, const int* __restrict__ permB,
    int M, int N,
    const float* __restrict__ rs, const float* __restrict__ bias,
    float* __restrict__ C, unsigned short* __restrict__ Th, unsigned short* __restrict__ Tl) {
  static_assert(KK % 32 == 0, "K");
  // XCD-aware swizzle (all launches have gridDim.x*gridDim.y % 8 == 0)
  const int gx = gridDim.x;
  int id = blockIdx.y * gx + blockIdx.x;
  int cpx = (gx * gridDim.y) >> 3;
  int sid = (id & 7) * cpx + (id >> 3);
  const int bx = sid % gx, by = sid / gx;
  const int z = (S > 1) ? blockIdx.z : 0;
  const int LDA = S * KK;
  const int wid = threadIdx.x >> 6, lane = threadIdx.x & 63;
  const int i0 = by * 64 + (wid >> 1) * 32;
  const int j0 = bx * 64 + (wid & 1) * 32;
  const int lr = lane & 15, lk = lane >> 4;
  size_t aoff[2], boff[2];
#pragma unroll
  for (int t = 0; t < 2; ++t) {
    int ia = i0 + 16 * t + lr;
    int ra = permA ? permA[ia] : ia;
    aoff[t] = (size_t)ra * LDA + z * KK + lk * 8;
    int jb = j0 + 16 * t + lr;
    int rb = permB ? permB[jb] : jb;
    boff[t] = (size_t)rb * LDA + z * KK + lk * 8;
  }
  const f32x4 zf = {0.f, 0.f, 0.f, 0.f};
  f32x4 acc[2][2];
  acc[0][0] = zf; acc[0][1] = zf; acc[1][0] = zf; acc[1][1] = zf;

  bf16x8 ahf[4][2], bhf[4][2], alf[4][2], blf[4][2];
  auto loadk = [&](int k0, int b) {
    ahf[b][0] = *(const bf16x8*)(Ah + aoff[0] + k0);
    ahf[b][1] = *(const bf16x8*)(Ah + aoff[1] + k0);
    bhf[b][0] = *(const bf16x8*)(Bh + boff[0] + k0);
    bhf[b][1] = *(const bf16x8*)(Bh + boff[1] + k0);
    if constexpr (AL) {
      alf[b][0] = *(const bf16x8*)(Al + aoff[0] + k0);
      alf[b][1] = *(const bf16x8*)(Al + aoff[1] + k0);
    }
    if constexpr (BL) {
      blf[b][0] = *(const bf16x8*)(Bl + boff[0] + k0);
      blf[b][1] = *(const bf16x8*)(Bl + boff[1] + k0);
    }
  };
  auto domm = [&](int b) {
#pragma unroll
    for (int am = 0; am < 2; ++am)
#pragma unroll
      for (int bn = 0; bn < 2; ++bn) {
        acc[am][bn] = __builtin_amdgcn_mfma_f32_16x16x32_bf16(ahf[b][am], bhf[b][bn], acc[am][bn], 0, 0, 0);
        if constexpr (BL)
          acc[am][bn] = __builtin_amdgcn_mfma_f32_16x16x32_bf16(ahf[b][am], blf[b][bn], acc[am][bn], 0, 0, 0);
        if constexpr (AL)
          acc[am][bn] = __builtin_amdgcn_mfma_f32_16x16x32_bf16(alf[b][am], bhf[b][bn], acc[am][bn], 0, 0, 0);
      }
  };

  loadk(0, 0);
  if constexpr (KK > 32) loadk(32, 1);
  if constexpr (KK > 64) loadk(64, 2);
#pragma unroll
  for (int k0 = 0; k0 < KK; k0 += 32) {
    const int cur = (k0 >> 5) & 3;
    if (k0 + 96 < KK) loadk(k0 + 96, (cur + 3) & 3);
    domm(cur);
  }

#pragma unroll
  for (int am = 0; am < 2; ++am)
#pragma unroll
    for (int bn = 0; bn < 2; ++bn) {
      int ib = i0 + 16 * am + lk * 4;
      int j = j0 + 16 * bn + lr;
      f32x4 a = acc[am][bn];
      if constexpr (S > 1) {
#pragma unroll
        for (int r = 0; r < 4; ++r) C[((size_t)z * M + ib + r) * N + j] = a[r];
      } else if constexpr (EPI == 0) {
#pragma unroll
        for (int r = 0; r < 4; ++r) C[(size_t)(ib + r) * N + j] = a[r];
      } else if constexpr (EPI == 1) {
#pragma unroll
        for (int r = 0; r < 4; ++r) C[(size_t)(ib + r) * N + j] = rs[ib + r] * a[r];
      } else if constexpr (EPI == 2) {
        unsigned long long hp = 0, lp = 0;
#pragma unroll
        for (int r = 0; r < 4; ++r) {
          unsigned short hv, lv;
          split2(rs[ib + r] * a[r], hv, lv);
          hp |= ((unsigned long long)hv) << (16 * r);
          lp |= ((unsigned long long)lv) << (16 * r);
        }
        *(unsigned long long*)&Th[(size_t)j * M + ib] = hp;
        *(unsigned long long*)&Tl[(size_t)j * M + ib] = lp;
      } else {
#pragma unroll
        for (int r = 0; r < 4; ++r)
          C[(size_t)(ib + r) * N + j] = fmaxf(rs[ib + r] * a[r] + bias[j], 0.0f);
      }
    }
}

// ---------------- launch ----------------

extern "C" void kernel_launch(void* const* d_in, const int* in_sizes, int n_in,
                              void* d_out, int out_size, void* d_ws, size_t ws_size,
                              hipStream_t stream) {
  (void)in_sizes; (void)n_in; (void)out_size; (void)ws_size;
  const float* x  = (const float*)d_in[0];
  const int* ei   = (const int*)d_in[1];
  const int* esrc = ei;
  const int* edst = ei + EE;
  const float* w0 = (const float*)d_in[2];
  const float* b0 = (const float*)d_in[3];
  const float* w1 = (const float*)d_in[4];
  const float* b1 = (const float*)d_in[5];
  const float* w2 = (const float*)d_in[6];
  const float* b2 = (const float*)d_in[7];
  const float* w3 = (const float*)d_in[8];
  const float* b3 = (const float*)d_in[9];
  const float* w4 = (const float*)d_in[10];
  const float* b4 = (const float*)d_in[11];
  const float* p0 = (const float*)d_in[12];
  const float* p1 = (const float*)d_in[13];
  float* out = (float*)d_out;

  char* ws = (char*)d_ws;
  size_t off = 0;
  auto alloc = [&](size_t b) { void* p = ws + off; off += (b + 255) & ~(size_t)255; return p; };

  int* csc_off = (int*)alloc(4 * (NN + 1));
  int* csr_off = (int*)alloc(4 * (NN + 1));
  int* csc_src = (int*)alloc(4 * EE);
  int* csr_dst = (int*)alloc(4 * EE);

  // zeroed region: counts + degs + ranks
  size_t zero_bytes = 4 * NN * 4 + 4 * NP1 + 4 * NP2 + 4 * NN + 4 * NP1;
  int* cnts    = (int*)alloc(zero_bytes);
  int* cnt_dst = cnts;
  int* cnt_src = cnts + NN;
  int* fill_dst = cnts + 2 * NN;
  int* fill_src = cnts + 3 * NN;
  float* deg1 = (float*)(cnts + 4 * NN);
  float* deg2 = deg1 + NP1;
  int* rank0 = (int*)(deg2 + NP2);
  int* rank1 = rank0 + NN;

  int* kept0 = (int*)alloc(4 * NN);
  int* perm0 = (int*)alloc(4 * NP1);
  int* kept1 = (int*)alloc(4 * NP1);
  int* perm1 = (int*)alloc(4 * NP2);
  float* dis0 = (float*)alloc(4 * NN);
  float* dis1 = (float*)alloc(4 * NP1);
  float* dis2 = (float*)alloc(4 * NP2);
  float* pnrm = (float*)alloc(8);
  float* s0   = (float*)alloc(4 * NN);
  float* vals0 = (float*)alloc(4 * NP1);
  float* s1   = (float*)alloc(4 * NP1);
  float* vals1 = (float*)alloc(4 * NP2);
  unsigned long long* keys0 = (unsigned long long*)alloc(8 * NN);
  unsigned long long* keys1 = (unsigned long long*)alloc(8 * NP1);

  const size_t MB = 1024 * 1024;
  // B1 region (16MB): B1 fp32 lives until b1_dual; then bytes 0..8MB host B2 + B2t
  // splits, bytes 8..16MB are the split-K partial scratch.
  char* regB1 = (char*)alloc(16 * MB);
  float* B1   = (float*)regB1;                       // 2048^2 fp32
  float* B2   = (float*)regB1;                       // 1024^2 fp32 (4MB)  [after B1 dead]
  unsigned short* B2th = (unsigned short*)(regB1 + 4 * MB);   // 2MB
  unsigned short* B2tl = (unsigned short*)(regB1 + 6 * MB);   // 2MB
  float* pscr = (float*)(regB1 + 8 * MB);            // 8MB split-K partials

  unsigned short* B1rm = (unsigned short*)alloc(8 * MB);  // 2048^2 bf16 row-major (exact)
  unsigned short* B1t  = (unsigned short*)alloc(8 * MB);  // 2048^2 bf16 transposed (exact)
  float* res0 = (float*)alloc(4 * MB);   // 4096x256
  float* res1 = (float*)alloc(4 * MB);   // 2048x512
  float* yreg = (float*)alloc(4 * MB);   // y0 (4096x256) then y4 (4096x128)
  float* outreg = (float*)alloc(2 * MB); // out2 (1024x512) then out3 (2048x256)
  float* out2 = outreg, *out3 = outreg;
  char* ytreg = (char*)alloc(4 * MB);    // Y1t h+l -> Y2t h+l -> Y3t h+l
  unsigned short* Y1th = (unsigned short*)ytreg;
  unsigned short* Y1tl = (unsigned short*)(ytreg + 2 * MB);
  unsigned short* Y2th = (unsigned short*)ytreg;
  unsigned short* Y2tl = (unsigned short*)(ytreg + 1 * MB);
  unsigned short* Y3th = (unsigned short*)ytreg;
  unsigned short* Y3tl = (unsigned short*)(ytreg + 1 * MB);
  char* xsreg = (char*)alloc(4 * MB);    // x3 h+l (2+2MB) -> x4 h+l (2+2MB)
  unsigned short* x3h = (unsigned short*)xsreg;
  unsigned short* x3l = (unsigned short*)(xsreg + 2 * MB);
  unsigned short* x4h = (unsigned short*)xsreg;
  unsigned short* x4l = (unsigned short*)(xsreg + 2 * MB);
  unsigned short* xh = (unsigned short*)alloc(1 * MB);   // 4096x128
  unsigned short* xl = (unsigned short*)alloc(1 * MB);
  char* xsm = (char*)alloc(2 * MB);      // x1 h+l (1+1MB) -> x2 h+l (1+1MB)
  unsigned short* x1h = (unsigned short*)xsm;
  unsigned short* x1l = (unsigned short*)(xsm + 1 * MB);
  unsigned short* x2h = (unsigned short*)xsm;
  unsigned short* x2l = (unsigned short*)(xsm + 1 * MB);
  // weights (transposed splits)
  unsigned short* Wt0h = (unsigned short*)alloc(256 * 128 * 2);
  unsigned short* Wt0l = (unsigned short*)alloc(256 * 128 * 2);
  unsigned short* Wt1h = (unsigned short*)alloc(512 * 256 * 2);
  unsigned short* Wt1l = (unsigned short*)alloc(512 * 256 * 2);
  unsigned short* Wt2h = (unsigned short*)alloc(512 * 512 * 2);
  unsigned short* Wt2l = (unsigned short*)alloc(512 * 512 * 2);
  unsigned short* Wt3h = (unsigned short*)alloc(256 * 512 * 2);
  unsigned short* Wt3l = (unsigned short*)alloc(256 * 512 * 2);
  unsigned short* Wt4h = (unsigned short*)alloc(128 * 256 * 2);
  unsigned short* Wt4l = (unsigned short*)alloc(128 * 256 * 2);

  hipMemsetAsync(cnts, 0, zero_bytes, stream);

  // graph build
  hist_kernel<<<EE / 256, 256, 0, stream>>>(esrc, edst, cnt_src, cnt_dst, EE);
  scan_kernel<<<1, 1024, 0, stream>>>(cnt_dst, csc_off, NN);
  scan_kernel<<<1, 1024, 0, stream>>>(cnt_src, csr_off, NN);
  scatter_kernel<<<EE / 256, 256, 0, stream>>>(esrc, edst, csc_off, csr_off,
                                               fill_dst, fill_src, csc_src, csr_dst, EE);
  dis0_kernel<<<NN / 256, 256, 0, stream>>>(cnt_dst, dis0, NN);
  pnorm_kernel<<<1, 256, 0, stream>>>(p0, pnrm + 0, 256);
  pnorm_kernel<<<1, 256, 0, stream>>>(p1, pnrm + 1, 512);

  // weight conversions
  tsplit<<<dim3(4, 2), 256, 0, stream>>>(w0, Wt0h, Wt0l, 128, 256);
  tsplit<<<dim3(8, 4), 256, 0, stream>>>(w1, Wt1h, Wt1l, 256, 512);
  tsplit<<<dim3(8, 8), 256, 0, stream>>>(w2, Wt2h, Wt2l, 512, 512);
  tsplit<<<dim3(4, 8), 256, 0, stream>>>(w3, Wt3h, Wt3l, 512, 256);
  tsplit<<<dim3(2, 4), 256, 0, stream>>>(w4, Wt4h, Wt4l, 256, 128);
  split_rm<<<(NN * 128) / 256, 256, 0, stream>>>(x, xh, xl, NN * 128);

  // gcn0
  gemm16<1, 1, 1, 128, 1><<<dim3(4, 64), 256, 0, stream>>>(xh, xl, Wt0h, Wt0l, nullptr, nullptr,
                                                           NN, 256, dis0, nullptr, yreg, nullptr, nullptr);
  spmm_gather_v<256><<<NN / 4, 256, 0, stream>>>(yreg, csc_off, csc_src, dis0, b0, res0);

  // pool0
  score_key<<<NN, 256, 0, stream>>>(res0, p0, pnrm + 0, s0, keys0, 256);
  rank_count<<<dim3(NN / 256, NN / 512), 256, 0, stream>>>(keys0, rank0);
  rank_place<<<NN / 256, 256, 0, stream>>>(s0, rank0, NP1, NN, kept0, perm0, vals0);
  pool_split<<<NP1, 256, 0, stream>>>(res0, perm0, vals0, x1h, x1l, 256);

  // augment0 -> B1 (+I folded), deg, dis; bf16 copies
  aug_row<<<NP1, 256, 0, stream>>>(csr_off, csr_dst, kept0, perm0, B1);
  colsum_part<<<dim3(NP1 / 256, NP1 / 16), 256, 0, stream>>>(B1, deg1, NP1);
  dis_from_deg<<<NP1 / 256, 256, 0, stream>>>(deg1, dis1, NP1);
  b1_dual<<<dim3(32, 32), 256, 0, stream>>>(B1, B1rm, B1t, NP1);
  // B1 fp32 dead after b1_dual.

  // gcn1
  gemm16<2, 1, 1, 256, 1><<<dim3(8, 32), 256, 0, stream>>>(x1h, x1l, Wt1h, Wt1l, nullptr, nullptr,
                                                           NP1, 512, dis1, nullptr, nullptr, Y1th, Y1tl);
  gemm16<0, 0, 1, 1024, 2><<<dim3(8, 32, 2), 256, 0, stream>>>(B1t, nullptr, Y1th, Y1tl, nullptr, nullptr,
                                                               NP1, 512, nullptr, nullptr, pscr, nullptr, nullptr);
  ep3<<<(NP1 * 512) / 1024, 256, 0, stream>>>(pscr, dis1, b1, res1, NP1, 512);

  // pool1
  score_key<<<NP1, 256, 0, stream>>>(res1, p1, pnrm + 1, s1, keys1, 512);
  rank_count<<<dim3(NP1 / 256, NP1 / 512), 256, 0, stream>>>(keys1, rank1);
  rank_place<<<NP1 / 256, 256, 0, stream>>>(s1, rank1, NP2, NP1, kept1, perm1, vals1);
  pool_split<<<NP2, 256, 0, stream>>>(res1, perm1, vals1, x2h, x2l, 512);

  // augment1 (dense, exact bf16, split-K): B2 = B1[perm1,:] @ B1[:,perm1] (+I)
  gemm16<0, 0, 0, 1024, 2><<<dim3(16, 16, 2), 256, 0, stream>>>(B1rm, nullptr, B1t, nullptr, perm1, perm1,
                                                                NP2, NP2, nullptr, nullptr, pscr, nullptr, nullptr);
  ep_aug<<<(NP2 * NP2) / 1024, 256, 0, stream>>>(pscr, B2, NP2);
  colsum_part<<<dim3(NP2 / 256, NP2 / 16), 256, 0, stream>>>(B2, deg2, NP2);
  dis_from_deg<<<NP2 / 256, 256, 0, stream>>>(deg2, dis2, NP2);
  tsplit<<<dim3(16, 16), 256, 0, stream>>>(B2, B2th, B2tl, NP2, NP2);

  // gcn2 (bottleneck)
  gemm16<2, 1, 1, 512, 1><<<dim3(8, 16), 256, 0, stream>>>(x2h, x2l, Wt2h, Wt2l, nullptr, nullptr,
                                                           NP2, 512, dis2, nullptr, nullptr, Y2th, Y2tl);
  gemm16<0, 1, 1, 512, 2><<<dim3(8, 16, 2), 256, 0, stream>>>(B2th, B2tl, Y2th, Y2tl, nullptr, nullptr,
                                                              NP2, 512, nullptr, nullptr, pscr, nullptr, nullptr);
  ep3<<<(NP2 * 512) / 1024, 256, 0, stream>>>(pscr, dis2, b2, out2, NP2, 512);

  // up1
  unpool_split<<<(NP1 * 512) / 256, 256, 0, stream>>>(res1, out2, kept1, x3h, x3l, NP1, 512);
  gemm16<2, 1, 1, 512, 1><<<dim3(4, 32), 256, 0, stream>>>(x3h, x3l, Wt3h, Wt3l, nullptr, nullptr,
                                                           NP1, 256, dis1, nullptr, nullptr, Y3th, Y3tl);
  gemm16<0, 0, 1, 1024, 2><<<dim3(4, 32, 2), 256, 0, stream>>>(B1t, nullptr, Y3th, Y3tl, nullptr, nullptr,
                                                               NP1, 256, nullptr, nullptr, pscr, nullptr, nullptr);
  ep3<<<(NP1 * 256) / 1024, 256, 0, stream>>>(pscr, dis1, b3, out3, NP1, 256);

  // up0
  unpool_split<<<(NN * 256) / 256, 256, 0, stream>>>(res0, out3, kept0, x4h, x4l, NN, 256);
  gemm16<1, 1, 1, 256, 1><<<dim3(2, 64), 256, 0, stream>>>(x4h, x4l, Wt4h, Wt4l, nullptr, nullptr,
                                                           NN, 128, dis0, nullptr, yreg, nullptr, nullptr);
  spmm_gather_v<128><<<NN / 4, 256, 0, stream>>>(yreg, csc_off, csc_src, dis0, b4, out);
}

// Round 6
// 377.164 us; speedup vs baseline: 2.8549x; 1.1427x over previous
//
#include <hip/hip_runtime.h>

#define NN 4096
#define EE 131072
#define NP1 2048
#define NP2 1024

typedef __attribute__((ext_vector_type(8))) __bf16 bf16x8;
typedef __attribute__((ext_vector_type(4))) float f32x4;
typedef __attribute__((ext_vector_type(8))) unsigned short ushort8;

static __device__ inline unsigned short bfbits(__bf16 b) {
  union { __bf16 x; unsigned short u; } c; c.x = b; return c.u;
}
static __device__ inline void split2(float v, unsigned short& h, unsigned short& l) {
  __bf16 hb = (__bf16)v;
  float hf = (float)hb;
  __bf16 lb = (__bf16)(v - hf);
  h = bfbits(hb); l = bfbits(lb);
}

// Packed fragment layout for a [R rows][K k] bf16 matrix (R%16==0, K%32==0):
// 16x32 tile (rt,kt) holds 64 chunks of 8 elems; chunk-in-tile = ((k>>3)&3)*16 + (r&15)
// == the MFMA lane id, so a wave's fragment load is 64 lanes * 16B contiguous.
static __device__ inline size_t pchunk(int r, int k, int NT) {
  return ((size_t)(r >> 4) * NT + (k >> 5)) * 64 + (((k >> 3) & 3) << 4) + (r & 15);
}

// ---------------- graph build ----------------

__global__ void hist_kernel(const int* __restrict__ src, const int* __restrict__ dst,
                            int* __restrict__ cnt_src, int* __restrict__ cnt_dst, int E) {
  int e = blockIdx.x * blockDim.x + threadIdx.x;
  if (e < E) {
    atomicAdd(&cnt_src[src[e]], 1);
    atomicAdd(&cnt_dst[dst[e]], 1);
  }
}

__global__ __launch_bounds__(1024) void scan_kernel(const int* __restrict__ in, int* __restrict__ out, int n) {
  __shared__ int tmp[4096];
  int tid = threadIdx.x;
  for (int i = tid; i < n; i += 1024) tmp[i] = in[i];
  __syncthreads();
  for (int off = 1; off < n; off <<= 1) {
    int v[4];
    int c = 0;
    for (int i = tid; i < n; i += 1024) { v[c++] = (i >= off) ? tmp[i - off] : 0; }
    __syncthreads();
    c = 0;
    for (int i = tid; i < n; i += 1024) { tmp[i] += v[c++]; }
    __syncthreads();
  }
  for (int i = tid; i < n; i += 1024) out[i + 1] = tmp[i];
  if (tid == 0) out[0] = 0;
}

__global__ void scatter_kernel(const int* __restrict__ src, const int* __restrict__ dst,
                               const int* __restrict__ csc_off, const int* __restrict__ csr_off,
                               int* __restrict__ fill_dst, int* __restrict__ fill_src,
                               int* __restrict__ csc_src, int* __restrict__ csr_dst, int E) {
  int e = blockIdx.x * blockDim.x + threadIdx.x;
  if (e < E) {
    int s = src[e], d = dst[e];
    int p = atomicAdd(&fill_dst[d], 1);
    csc_src[csc_off[d] + p] = s;
    int q = atomicAdd(&fill_src[s], 1);
    csr_dst[csr_off[s] + q] = d;
  }
}

__global__ void dis0_kernel(const int* __restrict__ cnt_dst, float* __restrict__ dis, int n) {
  int i = blockIdx.x * blockDim.x + threadIdx.x;
  if (i < n) dis[i] = rsqrtf((float)cnt_dst[i] + 1.0f);
}

__global__ void pnorm_kernel(const float* __restrict__ p, float* __restrict__ outv, int C) {
  int tid = threadIdx.x;
  float acc = 0.f;
  for (int j = tid; j < C; j += 256) { float v = p[j]; acc += v * v; }
  for (int o = 32; o > 0; o >>= 1) acc += __shfl_down(acc, o);
  __shared__ float red[4];
  if ((tid & 63) == 0) red[tid >> 6] = acc;
  __syncthreads();
  if (tid == 0) outv[0] = sqrtf(red[0] + red[1] + red[2] + red[3]);
}

// ---------------- scoring / topk ----------------

__global__ void score_key(const float* __restrict__ X, const float* __restrict__ p,
                          const float* __restrict__ pn, float* __restrict__ s,
                          unsigned long long* __restrict__ keys, int C) {
  int i = blockIdx.x;
  int tid = threadIdx.x;
  float acc = 0.f;
  for (int j = tid; j < C; j += 256) acc += X[(size_t)i * C + j] * p[j];
  for (int o = 32; o > 0; o >>= 1) acc += __shfl_down(acc, o);
  __shared__ float red[4];
  if ((tid & 63) == 0) red[tid >> 6] = acc;
  __syncthreads();
  if (tid == 0) {
    float sv = tanhf((red[0] + red[1] + red[2] + red[3]) / pn[0]);
    s[i] = sv;
    unsigned u = __float_as_uint(sv);
    unsigned m = (u & 0x80000000u) ? ~u : (u | 0x80000000u);
    keys[i] = (((unsigned long long)(~m)) << 32) | (unsigned)i;  // desc value, asc index
  }
}

__global__ __launch_bounds__(256) void rank_count(const unsigned long long* __restrict__ keys,
                                                  int* __restrict__ rank) {
  __shared__ unsigned long long kk[512];
  int tid = threadIdx.x;
  int cand = blockIdx.x * 256 + tid;
  int base = blockIdx.y * 512;
  kk[tid] = keys[base + tid];
  kk[tid + 256] = keys[base + tid + 256];
  __syncthreads();
  unsigned long long kc = keys[cand];
  int c = 0;
#pragma unroll 8
  for (int t = 0; t < 512; ++t) c += (kk[t] < kc) ? 1 : 0;
  atomicAdd(&rank[cand], c);
}

__global__ void rank_place(const float* __restrict__ s, const int* __restrict__ rank, int k, int n,
                           int* __restrict__ kept, int* __restrict__ perm, float* __restrict__ vals) {
  int i = blockIdx.x * blockDim.x + threadIdx.x;
  if (i < n) {
    int r = rank[i];
    if (r < k) { perm[r] = i; vals[r] = s[i]; kept[i] = r; }
    else kept[i] = -1;
  }
}

// pooled row gather + gate + bf16 split into PACKED layout
__global__ void pool_split_p(const float* __restrict__ X, const int* __restrict__ perm,
                             const float* __restrict__ vals, unsigned short* __restrict__ h,
                             unsigned short* __restrict__ l, int C) {
  int a = blockIdx.x;
  int r = perm[a];
  float v = vals[a];
  int NT = C >> 5;
  for (int j0 = threadIdx.x * 8; j0 < C; j0 += 64 * 8) {
    ushort8 hv, lv;
#pragma unroll
    for (int e = 0; e < 8; ++e) {
      unsigned short he, le;
      split2(X[(size_t)r * C + j0 + e] * v, he, le);
      hv[e] = he; lv[e] = le;
    }
    size_t c = pchunk(a, j0, NT);
    *(ushort8*)&h[c * 8] = hv;
    *(ushort8*)&l[c * 8] = lv;
  }
}

// ---------------- augment: row-parallel SpGEMM with LDS accumulator ----------------

__global__ __launch_bounds__(256) void aug_row(const int* __restrict__ csr_off,
                                               const int* __restrict__ csr_dst,
                                               const int* __restrict__ kept,
                                               const int* __restrict__ perm,
                                               float* __restrict__ B) {
  __shared__ float acc[NP1];
  int ki = blockIdx.x;
  int r = perm[ki];
  for (int t = threadIdx.x; t < NP1; t += 256) acc[t] = 0.f;
  __syncthreads();
  int s = csr_off[r], e = csr_off[r + 1];
  int nm = e - s;
  int wave = threadIdx.x >> 6, lane = threadIdx.x & 63;
  for (int m = wave; m <= nm; m += 4) {
    int k = (m < nm) ? csr_dst[s + m] : r;
    int s2 = csr_off[k], e2 = csr_off[k + 1];
    int n2 = e2 - s2;
    for (int t = lane; t <= n2; t += 64) {
      int j = (t < n2) ? csr_dst[s2 + t] : k;
      int kj = kept[j];
      if (kj >= 0) atomicAdd(&acc[kj], 1.0f);
    }
  }
  __syncthreads();
  if (threadIdx.x == 0) acc[ki] += 1.0f;
  __syncthreads();
  float* row = B + (size_t)ki * NP1;
  for (int t = threadIdx.x; t < NP1; t += 256) row[t] = acc[t];
}

__global__ void colsum_part(const float* __restrict__ B, float* __restrict__ deg, int n) {
  int c = blockIdx.x * blockDim.x + threadIdx.x;
  int r0 = blockIdx.y * 16;
  float acc = 0.f;
#pragma unroll
  for (int r = 0; r < 16; ++r) acc += B[(size_t)(r0 + r) * n + c];
  atomicAdd(&deg[c], acc);
}

__global__ void dis_from_deg(const float* __restrict__ deg, float* __restrict__ dis, int n) {
  int i = blockIdx.x * blockDim.x + threadIdx.x;
  if (i < n) dis[i] = rsqrtf(deg[i]);
}

// ---------------- conversions (all emit packed layout) ----------------

// fp32 row-major [R][K] -> packed bf16 hi/lo
__global__ void split_p(const float* __restrict__ in, unsigned short* __restrict__ h,
                        unsigned short* __restrict__ l, int K) {
  int c = blockIdx.x * blockDim.x + threadIdx.x;  // chunk index
  int lane = c & 63, tile = c >> 6;
  int NT = K >> 5;
  int kt = tile % NT, rt = tile / NT;
  int r = rt * 16 + (lane & 15);
  int k = kt * 32 + (lane >> 4) * 8;
  const float* p = in + (size_t)r * K + k;
  ushort8 hv, lv;
#pragma unroll
  for (int e = 0; e < 8; ++e) {
    unsigned short he, le;
    split2(p[e], he, le);
    hv[e] = he; lv[e] = le;
  }
  *(ushort8*)&h[(size_t)c * 8] = hv;
  *(ushort8*)&l[(size_t)c * 8] = lv;
}

// fp32 [R][C] -> packed of the TRANSPOSE ([C rows][R k]) hi/lo
__global__ void tsplit_p(const float* __restrict__ in, unsigned short* __restrict__ oh,
                         unsigned short* __restrict__ ol, int R, int C) {
  int c = blockIdx.x * blockDim.x + threadIdx.x;
  int lane = c & 63, tile = c >> 6;
  int NT = R >> 5;
  int kt = tile % NT, jt = tile / NT;
  int j = jt * 16 + (lane & 15);
  int k = kt * 32 + (lane >> 4) * 8;
  ushort8 hv, lv;
#pragma unroll
  for (int e = 0; e < 8; ++e) {
    unsigned short he, le;
    split2(in[(size_t)(k + e) * C + j], he, le);
    hv[e] = he; lv[e] = le;
  }
  *(ushort8*)&oh[(size_t)c * 8] = hv;
  *(ushort8*)&ol[(size_t)c * 8] = lv;
}

// B1 fp32 [n][n] -> packed bf16 row-major AND packed bf16 transpose (exact ints)
__global__ __launch_bounds__(256) void b1_dual_p(const float* __restrict__ in,
                                                 unsigned short* __restrict__ rm,
                                                 unsigned short* __restrict__ tr, int n) {
  __shared__ float t[64][65];
  int r0 = blockIdx.y * 64, c0 = blockIdx.x * 64;
  int tid = threadIdx.x;
  int NT = n >> 5;
#pragma unroll
  for (int q = 0; q < 16; ++q) {
    int idx = q * 256 + tid;
    int rr = idx >> 6, cc = idx & 63;
    t[rr][cc] = in[(size_t)(r0 + rr) * n + c0 + cc];
  }
  __syncthreads();
#pragma unroll
  for (int q2 = tid; q2 < 512; q2 += 256) {
    int rr = q2 >> 3, cc8 = q2 & 7;
    ushort8 hv;
#pragma unroll
    for (int e = 0; e < 8; ++e) hv[e] = bfbits((__bf16)t[rr][cc8 * 8 + e]);
    *(ushort8*)&rm[pchunk(r0 + rr, c0 + cc8 * 8, NT) * 8] = hv;
  }
#pragma unroll
  for (int q2 = tid; q2 < 512; q2 += 256) {
    int cc = q2 >> 3, rr8 = q2 & 7;
    ushort8 hv;
#pragma unroll
    for (int e = 0; e < 8; ++e) hv[e] = bfbits((__bf16)t[rr8 * 8 + e][cc]);
    *(ushort8*)&tr[pchunk(c0 + cc, r0 + rr8 * 8, NT) * 8] = hv;
  }
}

// packed row-gather: out packed row a = in packed row perm[a]
__global__ void gather_p(const unsigned short* __restrict__ in, const int* __restrict__ perm,
                         unsigned short* __restrict__ outp, int NT) {
  int c = blockIdx.x * blockDim.x + threadIdx.x;
  int lane = c & 63, tile = c >> 6;
  int kt = tile % NT, at = tile / NT;
  int a = at * 16 + (lane & 15);
  int sub = lane >> 4;
  int p = perm[a];
  size_t sc = ((size_t)(p >> 4) * NT + kt) * 64 + sub * 16 + (p & 15);
  *(ushort8*)&outp[(size_t)c * 8] = *(const ushort8*)&in[sc * 8];
}

// up-path input: res + scatter(up), emitted as packed bf16 hi/lo
__global__ void unpool_split_p(const float* __restrict__ res, const float* __restrict__ up,
                               const int* __restrict__ kept, unsigned short* __restrict__ h,
                               unsigned short* __restrict__ l, int C) {
  int c = blockIdx.x * blockDim.x + threadIdx.x;
  int lane = c & 63, tile = c >> 6;
  int NT = C >> 5;
  int kt = tile % NT, rt = tile / NT;
  int r = rt * 16 + (lane & 15);
  int j0 = kt * 32 + (lane >> 4) * 8;
  int kv = kept[r];
  ushort8 hv, lv;
#pragma unroll
  for (int e = 0; e < 8; ++e) {
    float v = res[(size_t)r * C + j0 + e];
    if (kv >= 0) v += up[(size_t)kv * C + j0 + e];
    unsigned short he, le;
    split2(v, he, le);
    hv[e] = he; lv[e] = le;
  }
  *(ushort8*)&h[(size_t)c * 8] = hv;
  *(ushort8*)&l[(size_t)c * 8] = lv;
}

// ---------------- misc ----------------

template <int C>
__global__ __launch_bounds__(256) void spmm_gather_v(const float* __restrict__ Y,
                                                     const int* __restrict__ off,
                                                     const int* __restrict__ srcs,
                                                     const float* __restrict__ dis,
                                                     const float* __restrict__ bias,
                                                     float* __restrict__ out) {
  constexpr int VEC = C / 64;
  int w = threadIdx.x >> 6, lane = threadIdx.x & 63;
  int c = blockIdx.x * 4 + w;
  int j = lane * VEC;
  float acc[VEC];
  const float* p = Y + (size_t)c * C + j;
#pragma unroll
  for (int u = 0; u < VEC; ++u) acc[u] = p[u];
  int s = off[c], e = off[c + 1];
  for (int t = s; t < e; ++t) {
    const float* q = Y + (size_t)srcs[t] * C + j;
#pragma unroll
    for (int u = 0; u < VEC; ++u) acc[u] += q[u];
  }
  float d = dis[c];
  float* o = out + (size_t)c * C + j;
#pragma unroll
  for (int u = 0; u < VEC; ++u) o[u] = fmaxf(d * acc[u] + bias[j + u], 0.0f);
}

// split-K combine: out = relu(rs*(p0+p1) + bias)
__global__ void ep3(const float* __restrict__ p, const float* __restrict__ rs,
                    const float* __restrict__ bias, float* __restrict__ outp, int M, int N) {
  int idx = blockIdx.x * blockDim.x + threadIdx.x;
  int j4 = (idx * 4) % N, i = (idx * 4) / N;
  float4 a = *(const float4*)(p + (size_t)i * N + j4);
  float4 b = *(const float4*)(p + (size_t)(M + i) * N + j4);
  float r = rs[i];
  float4 o;
  o.x = fmaxf(r * (a.x + b.x) + bias[j4 + 0], 0.f);
  o.y = fmaxf(r * (a.y + b.y) + bias[j4 + 1], 0.f);
  o.z = fmaxf(r * (a.z + b.z) + bias[j4 + 2], 0.f);
  o.w = fmaxf(r * (a.w + b.w) + bias[j4 + 3], 0.f);
  *(float4*)(outp + (size_t)i * N + j4) = o;
}

// split-K combine for augment: B = p0+p1 (+I)
__global__ void ep_aug(const float* __restrict__ p, float* __restrict__ B, int n) {
  int idx = blockIdx.x * blockDim.x + threadIdx.x;
  int j4 = (idx * 4) % n, i = (idx * 4) / n;
  float4 a = *(const float4*)(p + (size_t)i * n + j4);
  float4 b = *(const float4*)(p + (size_t)(n + i) * n + j4);
  float4 o = {a.x + b.x, a.y + b.y, a.z + b.z, a.w + b.w};
  if (i >= j4 && i < j4 + 4) (&o.x)[i - j4] += 1.0f;
  *(float4*)(B + (size_t)i * n + j4) = o;
}

// ---------------- bf16-split MFMA GEMM on packed operands ----------------
// C[i][j] = sum_k A[i][k]*B^T[j][k]; A,B packed; wave=32x32, block=64x64 tile.
// S>1: partial to C + z*M*N. S==1 EPI: 0 plain; 1 rowscale; 2 rowscale + packed-split transpose out
template <int EPI, int AL, int BL, int KK, int S>
__global__ __launch_bounds__(256) void gemm16(
    const unsigned short* __restrict__ Ah, const unsigned short* __restrict__ Al,
    const unsigned short* __restrict__ Bh, const unsigned short* __restrict__ Bl,
    int M, int N, const float* __restrict__ rs,
    float* __restrict__ C, unsigned short* __restrict__ Th, unsigned short* __restrict__ Tl) {
  static_assert(KK % 32 == 0, "K");
  constexpr int KSTEPS = KK / 32;
  const int NT = (KK * S) >> 5;
  // XCD-aware swizzle (all launches have gridDim.x*gridDim.y % 8 == 0)
  const int gx = gridDim.x;
  int id = blockIdx.y * gx + blockIdx.x;
  int cpx = (gx * gridDim.y) >> 3;
  int sid = (id & 7) * cpx + (id >> 3);
  const int bx = sid % gx, by = sid / gx;
  const int z = (S > 1) ? blockIdx.z : 0;
  const int wid = threadIdx.x >> 6, lane = threadIdx.x & 63;
  const int i0 = by * 64 + (wid >> 1) * 32;
  const int j0 = bx * 64 + (wid & 1) * 32;
  const int lr = lane & 15, lk = lane >> 4;
  size_t aoff[2], boff[2];
#pragma unroll
  for (int t = 0; t < 2; ++t) {
    aoff[t] = ((size_t)((i0 >> 4) + t) * NT + z * (KK >> 5)) * 512 + lane * 8;
    boff[t] = ((size_t)((j0 >> 4) + t) * NT + z * (KK >> 5)) * 512 + lane * 8;
  }
  const f32x4 zf = {0.f, 0.f, 0.f, 0.f};
  f32x4 acc[2][2];
  acc[0][0] = zf; acc[0][1] = zf; acc[1][0] = zf; acc[1][1] = zf;

  bf16x8 ahf[4][2], bhf[4][2], alf[4][2], blf[4][2];
  auto loadk = [&](int kk, int b) {
    size_t o = (size_t)kk * 512;
    ahf[b][0] = *(const bf16x8*)(Ah + aoff[0] + o);
    ahf[b][1] = *(const bf16x8*)(Ah + aoff[1] + o);
    bhf[b][0] = *(const bf16x8*)(Bh + boff[0] + o);
    bhf[b][1] = *(const bf16x8*)(Bh + boff[1] + o);
    if constexpr (AL) {
      alf[b][0] = *(const bf16x8*)(Al + aoff[0] + o);
      alf[b][1] = *(const bf16x8*)(Al + aoff[1] + o);
    }
    if constexpr (BL) {
      blf[b][0] = *(const bf16x8*)(Bl + boff[0] + o);
      blf[b][1] = *(const bf16x8*)(Bl + boff[1] + o);
    }
  };
  auto domm = [&](int b) {
#pragma unroll
    for (int am = 0; am < 2; ++am)
#pragma unroll
      for (int bn = 0; bn < 2; ++bn) {
        acc[am][bn] = __builtin_amdgcn_mfma_f32_16x16x32_bf16(ahf[b][am], bhf[b][bn], acc[am][bn], 0, 0, 0);
        if constexpr (BL)
          acc[am][bn] = __builtin_amdgcn_mfma_f32_16x16x32_bf16(ahf[b][am], blf[b][bn], acc[am][bn], 0, 0, 0);
        if constexpr (AL)
          acc[am][bn] = __builtin_amdgcn_mfma_f32_16x16x32_bf16(alf[b][am], bhf[b][bn], acc[am][bn], 0, 0, 0);
      }
  };

  loadk(0, 0);
  if constexpr (KSTEPS > 1) loadk(1, 1);
  if constexpr (KSTEPS > 2) loadk(2, 2);
#pragma unroll
  for (int kk = 0; kk < KSTEPS; ++kk) {
    const int cur = kk & 3;
    if (kk + 3 < KSTEPS) loadk(kk + 3, (cur + 3) & 3);
    domm(cur);
  }

#pragma unroll
  for (int am = 0; am < 2; ++am)
#pragma unroll
    for (int bn = 0; bn < 2; ++bn) {
      int ib = i0 + 16 * am + lk * 4;
      int j = j0 + 16 * bn + lr;
      f32x4 a = acc[am][bn];
      if constexpr (S > 1) {
#pragma unroll
        for (int r = 0; r < 4; ++r) C[((size_t)z * M + ib + r) * N + j] = a[r];
      } else if constexpr (EPI == 0) {
#pragma unroll
        for (int r = 0; r < 4; ++r) C[(size_t)(ib + r) * N + j] = a[r];
      } else if constexpr (EPI == 1) {
#pragma unroll
        for (int r = 0; r < 4; ++r) C[(size_t)(ib + r) * N + j] = rs[ib + r] * a[r];
      } else {
        unsigned long long hp = 0, lp = 0;
#pragma unroll
        for (int r = 0; r < 4; ++r) {
          unsigned short hv, lv;
          split2(rs[ib + r] * a[r], hv, lv);
          hp |= ((unsigned long long)hv) << (16 * r);
          lp |= ((unsigned long long)lv) << (16 * r);
        }
        size_t c = pchunk(j, ib, M >> 5);
        *(unsigned long long*)&Th[c * 8 + (ib & 7)] = hp;
        *(unsigned long long*)&Tl[c * 8 + (ib & 7)] = lp;
      }
    }
}

// ---------------- launch ----------------

extern "C" void kernel_launch(void* const* d_in, const int* in_sizes, int n_in,
                              void* d_out, int out_size, void* d_ws, size_t ws_size,
                              hipStream_t stream) {
  (void)in_sizes; (void)n_in; (void)out_size; (void)ws_size;
  const float* x  = (const float*)d_in[0];
  const int* ei   = (const int*)d_in[1];
  const int* esrc = ei;
  const int* edst = ei + EE;
  const float* w0 = (const float*)d_in[2];
  const float* b0 = (const float*)d_in[3];
  const float* w1 = (const float*)d_in[4];
  const float* b1 = (const float*)d_in[5];
  const float* w2 = (const float*)d_in[6];
  const float* b2 = (const float*)d_in[7];
  const float* w3 = (const float*)d_in[8];
  const float* b3 = (const float*)d_in[9];
  const float* w4 = (const float*)d_in[10];
  const float* b4 = (const float*)d_in[11];
  const float* p0 = (const float*)d_in[12];
  const float* p1 = (const float*)d_in[13];
  float* out = (float*)d_out;

  char* ws = (char*)d_ws;
  size_t off = 0;
  auto alloc = [&](size_t b) { void* p = ws + off; off += (b + 255) & ~(size_t)255; return p; };

  int* csc_off = (int*)alloc(4 * (NN + 1));
  int* csr_off = (int*)alloc(4 * (NN + 1));
  int* csc_src = (int*)alloc(4 * EE);
  int* csr_dst = (int*)alloc(4 * EE);

  size_t zero_bytes = 4 * NN * 4 + 4 * NP1 + 4 * NP2 + 4 * NN + 4 * NP1;
  int* cnts    = (int*)alloc(zero_bytes);
  int* cnt_dst = cnts;
  int* cnt_src = cnts + NN;
  int* fill_dst = cnts + 2 * NN;
  int* fill_src = cnts + 3 * NN;
  float* deg1 = (float*)(cnts + 4 * NN);
  float* deg2 = deg1 + NP1;
  int* rank0 = (int*)(deg2 + NP2);
  int* rank1 = rank0 + NN;

  int* kept0 = (int*)alloc(4 * NN);
  int* perm0 = (int*)alloc(4 * NP1);
  int* kept1 = (int*)alloc(4 * NP1);
  int* perm1 = (int*)alloc(4 * NP2);
  float* dis0 = (float*)alloc(4 * NN);
  float* dis1 = (float*)alloc(4 * NP1);
  float* dis2 = (float*)alloc(4 * NP2);
  float* pnrm = (float*)alloc(8);
  float* s0   = (float*)alloc(4 * NN);
  float* vals0 = (float*)alloc(4 * NP1);
  float* s1   = (float*)alloc(4 * NP1);
  float* vals1 = (float*)alloc(4 * NP2);
  unsigned long long* keys0 = (unsigned long long*)alloc(8 * NN);
  unsigned long long* keys1 = (unsigned long long*)alloc(8 * NP1);

  const size_t MB = 1024 * 1024;
  // B1 region (16MB): B1 fp32 until b1_dual_p; then Gh/Hh gathers (0..8MB) + pscr (8..16MB);
  // then B2 fp32 (0..4MB) + B2t splits (4..8MB).
  char* regB1 = (char*)alloc(16 * MB);
  float* B1   = (float*)regB1;
  unsigned short* Gh = (unsigned short*)regB1;            // 4MB gathered B1rm_p rows
  unsigned short* Hh = (unsigned short*)(regB1 + 4 * MB); // 4MB gathered B1t_p rows
  float* B2   = (float*)regB1;                            // after Gh dead
  unsigned short* B2th = (unsigned short*)(regB1 + 4 * MB);
  unsigned short* B2tl = (unsigned short*)(regB1 + 6 * MB);
  float* pscr = (float*)(regB1 + 8 * MB);                 // 8MB split-K partials

  unsigned short* B1rm = (unsigned short*)alloc(8 * MB);  // packed bf16 (exact)
  unsigned short* B1t  = (unsigned short*)alloc(8 * MB);  // packed bf16 transpose (exact)
  float* res0 = (float*)alloc(4 * MB);
  float* res1 = (float*)alloc(4 * MB);
  float* yreg = (float*)alloc(4 * MB);
  float* outreg = (float*)alloc(2 * MB);
  float* out2 = outreg, *out3 = outreg;
  char* ytreg = (char*)alloc(4 * MB);
  unsigned short* Y1th = (unsigned short*)ytreg;
  unsigned short* Y1tl = (unsigned short*)(ytreg + 2 * MB);
  unsigned short* Y2th = (unsigned short*)ytreg;
  unsigned short* Y2tl = (unsigned short*)(ytreg + 1 * MB);
  unsigned short* Y3th = (unsigned short*)ytreg;
  unsigned short* Y3tl = (unsigned short*)(ytreg + 1 * MB);
  char* xsreg = (char*)alloc(4 * MB);
  unsigned short* x3h = (unsigned short*)xsreg;
  unsigned short* x3l = (unsigned short*)(xsreg + 2 * MB);
  unsigned short* x4h = (unsigned short*)xsreg;
  unsigned short* x4l = (unsigned short*)(xsreg + 2 * MB);
  unsigned short* xh = (unsigned short*)alloc(1 * MB);
  unsigned short* xl = (unsigned short*)alloc(1 * MB);
  char* xsm = (char*)alloc(2 * MB);
  unsigned short* x1h = (unsigned short*)xsm;
  unsigned short* x1l = (unsigned short*)(xsm + 1 * MB);
  unsigned short* x2h = (unsigned short*)xsm;
  unsigned short* x2l = (unsigned short*)(xsm + 1 * MB);
  unsigned short* Wt0h = (unsigned short*)alloc(256 * 128 * 2);
  unsigned short* Wt0l = (unsigned short*)alloc(256 * 128 * 2);
  unsigned short* Wt1h = (unsigned short*)alloc(512 * 256 * 2);
  unsigned short* Wt1l = (unsigned short*)alloc(512 * 256 * 2);
  unsigned short* Wt2h = (unsigned short*)alloc(512 * 512 * 2);
  unsigned short* Wt2l = (unsigned short*)alloc(512 * 512 * 2);
  unsigned short* Wt3h = (unsigned short*)alloc(256 * 512 * 2);
  unsigned short* Wt3l = (unsigned short*)alloc(256 * 512 * 2);
  unsigned short* Wt4h = (unsigned short*)alloc(128 * 256 * 2);
  unsigned short* Wt4l = (unsigned short*)alloc(128 * 256 * 2);

  hipMemsetAsync(cnts, 0, zero_bytes, stream);

  // graph build
  hist_kernel<<<EE / 256, 256, 0, stream>>>(esrc, edst, cnt_src, cnt_dst, EE);
  scan_kernel<<<1, 1024, 0, stream>>>(cnt_dst, csc_off, NN);
  scan_kernel<<<1, 1024, 0, stream>>>(cnt_src, csr_off, NN);
  scatter_kernel<<<EE / 256, 256, 0, stream>>>(esrc, edst, csc_off, csr_off,
                                               fill_dst, fill_src, csc_src, csr_dst, EE);
  dis0_kernel<<<NN / 256, 256, 0, stream>>>(cnt_dst, dis0, NN);
  pnorm_kernel<<<1, 256, 0, stream>>>(p0, pnrm + 0, 256);
  pnorm_kernel<<<1, 256, 0, stream>>>(p1, pnrm + 1, 512);

  // operand conversions (packed)
  tsplit_p<<<(256 * 128 / 8) / 256, 256, 0, stream>>>(w0, Wt0h, Wt0l, 128, 256);
  tsplit_p<<<(512 * 256 / 8) / 256, 256, 0, stream>>>(w1, Wt1h, Wt1l, 256, 512);
  tsplit_p<<<(512 * 512 / 8) / 256, 256, 0, stream>>>(w2, Wt2h, Wt2l, 512, 512);
  tsplit_p<<<(256 * 512 / 8) / 256, 256, 0, stream>>>(w3, Wt3h, Wt3l, 512, 256);
  tsplit_p<<<(128 * 256 / 8) / 256, 256, 0, stream>>>(w4, Wt4h, Wt4l, 256, 128);
  split_p<<<(NN * 128 / 8) / 256, 256, 0, stream>>>(x, xh, xl, 128);

  // gcn0
  gemm16<1, 1, 1, 128, 1><<<dim3(4, 64), 256, 0, stream>>>(xh, xl, Wt0h, Wt0l,
                                                           NN, 256, dis0, yreg, nullptr, nullptr);
  spmm_gather_v<256><<<NN / 4, 256, 0, stream>>>(yreg, csc_off, csc_src, dis0, b0, res0);

  // pool0
  score_key<<<NN, 256, 0, stream>>>(res0, p0, pnrm + 0, s0, keys0, 256);
  rank_count<<<dim3(NN / 256, NN / 512), 256, 0, stream>>>(keys0, rank0);
  rank_place<<<NN / 256, 256, 0, stream>>>(s0, rank0, NP1, NN, kept0, perm0, vals0);
  pool_split_p<<<NP1, 64, 0, stream>>>(res0, perm0, vals0, x1h, x1l, 256);

  // augment0 -> B1 (+I folded), deg, dis; packed bf16 copies
  aug_row<<<NP1, 256, 0, stream>>>(csr_off, csr_dst, kept0, perm0, B1);
  colsum_part<<<dim3(NP1 / 256, NP1 / 16), 256, 0, stream>>>(B1, deg1, NP1);
  dis_from_deg<<<NP1 / 256, 256, 0, stream>>>(deg1, dis1, NP1);
  b1_dual_p<<<dim3(32, 32), 256, 0, stream>>>(B1, B1rm, B1t, NP1);
  // B1 fp32 dead after b1_dual_p.

  // gcn1
  gemm16<2, 1, 1, 256, 1><<<dim3(8, 32), 256, 0, stream>>>(x1h, x1l, Wt1h, Wt1l,
                                                           NP1, 512, dis1, nullptr, Y1th, Y1tl);
  gemm16<0, 0, 1, 1024, 2><<<dim3(8, 32, 2), 256, 0, stream>>>(B1t, nullptr, Y1th, Y1tl,
                                                               NP1, 512, nullptr, pscr, nullptr, nullptr);
  ep3<<<(NP1 * 512) / 1024, 256, 0, stream>>>(pscr, dis1, b1, res1, NP1, 512);

  // pool1
  score_key<<<NP1, 256, 0, stream>>>(res1, p1, pnrm + 1, s1, keys1, 512);
  rank_count<<<dim3(NP1 / 256, NP1 / 512), 256, 0, stream>>>(keys1, rank1);
  rank_place<<<NP1 / 256, 256, 0, stream>>>(s1, rank1, NP2, NP1, kept1, perm1, vals1);
  pool_split_p<<<NP2, 64, 0, stream>>>(res1, perm1, vals1, x2h, x2l, 512);

  // augment1: materialize gathered packed operands, then dense exact GEMM (split-K)
  gather_p<<<(NP2 * NP1 / 8) / 256, 256, 0, stream>>>(B1rm, perm1, Gh, NP1 >> 5);
  gather_p<<<(NP2 * NP1 / 8) / 256, 256, 0, stream>>>(B1t, perm1, Hh, NP1 >> 5);
  gemm16<0, 0, 0, 1024, 2><<<dim3(16, 16, 2), 256, 0, stream>>>(Gh, nullptr, Hh, nullptr,
                                                                NP2, NP2, nullptr, pscr, nullptr, nullptr);
  ep_aug<<<(NP2 * NP2) / 1024, 256, 0, stream>>>(pscr, B2, NP2);
  colsum_part<<<dim3(NP2 / 256, NP2 / 16), 256, 0, stream>>>(B2, deg2, NP2);
  dis_from_deg<<<NP2 / 256, 256, 0, stream>>>(deg2, dis2, NP2);
  tsplit_p<<<(NP2 * NP2 / 8) / 256, 256, 0, stream>>>(B2, B2th, B2tl, NP2, NP2);

  // gcn2 (bottleneck)
  gemm16<2, 1, 1, 512, 1><<<dim3(8, 16), 256, 0, stream>>>(x2h, x2l, Wt2h, Wt2l,
                                                           NP2, 512, dis2, nullptr, Y2th, Y2tl);
  gemm16<0, 1, 1, 512, 2><<<dim3(8, 16, 2), 256, 0, stream>>>(B2th, B2tl, Y2th, Y2tl,
                                                              NP2, 512, nullptr, pscr, nullptr, nullptr);
  ep3<<<(NP2 * 512) / 1024, 256, 0, stream>>>(pscr, dis2, b2, out2, NP2, 512);

  // up1
  unpool_split_p<<<(NP1 * 512 / 8) / 256, 256, 0, stream>>>(res1, out2, kept1, x3h, x3l, 512);
  gemm16<2, 1, 1, 512, 1><<<dim3(4, 32), 256, 0, stream>>>(x3h, x3l, Wt3h, Wt3l,
                                                           NP1, 256, dis1, nullptr, Y3th, Y3tl);
  gemm16<0, 0, 1, 1024, 2><<<dim3(4, 32, 2), 256, 0, stream>>>(B1t, nullptr, Y3th, Y3tl,
                                                               NP1, 256, nullptr, pscr, nullptr, nullptr);
  ep3<<<(NP1 * 256) / 1024, 256, 0, stream>>>(pscr, dis1, b3, out3, NP1, 256);

  // up0
  unpool_split_p<<<(NN * 256 / 8) / 256, 256, 0, stream>>>(res0, out3, kept0, x4h, x4l, 256);
  gemm16<1, 1, 1, 256, 1><<<dim3(2, 64), 256, 0, stream>>>(x4h, x4l, Wt4h, Wt4l,
                                                           NN, 128, dis0, yreg, nullptr, nullptr);
  spmm_gather_v<128><<<NN / 4, 256, 0, stream>>>(yreg, csc_off, csc_src, dis0, b4, out);
}